// Round 12
// baseline (3034.451 us; speedup 1.0000x reference)
//
#include <hip/hip_runtime.h>
#include <stdint.h>

// Seq_CNN_Big_Attention: qkv 1x5 conv (reflect pad) -> flash attn (head dim 512)
// -> 8x5 out conv. bf16 MFMA pipeline, per-batch sequential to bound ws.
// R12: operands that are XCD-L2-resident skip LDS:
//   k_attn: V read direct from L2 in PV (Vt removed, K double-buffered; stageK
//           at B1 so its transitive vmcnt wait is free). LDS traffic ~halved.
//   k_outconv: W-frags global->reg ISSUED BEFORE stageA (R8 had FIFO order
//           backwards); Bs removed.
// Workspace (uses 130 MB):
//   [0,32M)    Qg bf16 [8][4096][512]  (f = d*8+m, pre-scaled 0.125*log2e)
//   [32M,64M)  Kg bf16 [8][4096][512]
//   [64M,96M)  Vg bf16 [8][512][4096]  (transposed: PV reads 16B/lane direct)
//   [96M,128M) AO bf16 [4096][4096]    (feat = ic*8+mi); xb bf16 [4096][8][128]
//              overlays AO during k_convx/k_qkv (AO written later by k_attn)
//   [128M,130M) WB1 bf16 [1536][640]   (qkv weights, k = t*128+ci)
//   WB2 bf16 [1024][20480] overlays Qg/Kg during k_outconv (reconverted per b)

typedef __attribute__((ext_vector_type(8))) short short8;
typedef __attribute__((ext_vector_type(4))) short short4v;
typedef __attribute__((ext_vector_type(2))) short short2v;
typedef __attribute__((ext_vector_type(4))) float f32x4;
typedef __attribute__((ext_vector_type(16))) float f32x16;

__device__ __forceinline__ f32x4 mfma16(short8 a, short8 b, f32x4 c) {
  return __builtin_amdgcn_mfma_f32_16x16x32_bf16(a, b, c, 0, 0, 0);
}
__device__ __forceinline__ f32x16 mfma32(short8 a, short8 b, f32x16 c) {
  return __builtin_amdgcn_mfma_f32_32x32x16_bf16(a, b, c, 0, 0, 0);
}

__device__ __forceinline__ unsigned short f2bf(float f) {  // RNE f32->bf16
  union { float f; uint32_t u; } v; v.f = f;
  uint32_t r = (v.u + 0x7fffu + ((v.u >> 16) & 1u)) >> 16;
  return (unsigned short)r;
}

__device__ __forceinline__ uint32_t cvtpk(float lo, float hi) {
  uint32_t r;
  asm volatile("v_cvt_pk_bf16_f32 %0, %1, %2" : "=v"(r) : "v"(lo), "v"(hi));
  return r;
}
__device__ __forceinline__ void plswap(uint32_t& a, uint32_t& b) {
  asm volatile("v_permlane32_swap_b32 %0, %1" : "+v"(a), "+v"(b));
}

__device__ __forceinline__ int refl4096(int p) {  // reflect pad-2 index
  p = p < 0 ? -p : p;
  return p >= 4096 ? 8190 - p : p;
}

__device__ __forceinline__ void gl_lds16(const void* g, void* l) {
  __builtin_amdgcn_global_load_lds(
      (const __attribute__((address_space(1))) void*)g,
      (__attribute__((address_space(3))) void*)l, 16, 0, 0);
}

// ---------------- converters ----------------
__global__ void k_convw_qkv(const float* __restrict__ Wq,
                            const float* __restrict__ Wkv,
                            unsigned short* __restrict__ out) {
  int e = blockIdx.x * 256 + threadIdx.x;  // 1536*640 exact
  int oc = e / 640, k = e - oc * 640;
  int ci = k & 127, t = k >> 7;
  float w = (oc < 512) ? Wq[oc * 640 + ci * 5 + t]
                       : Wkv[(oc - 512) * 640 + ci * 5 + t];
  out[e] = f2bf(w);
}

// x (f32, one batch) -> xb bf16 [n][m][c] contiguous
__global__ __launch_bounds__(256)
void k_convx(const float* __restrict__ x, unsigned short* __restrict__ xb,
             int b) {
  int e = (blockIdx.x * 256 + threadIdx.x) * 8;  // 4194304 per batch
  const float* src = x + (size_t)b * 4194304 + e;
  f32x4 v0 = *(const f32x4*)src;
  f32x4 v1 = *(const f32x4*)(src + 4);
  short8 pk;
  pk[0] = (short)f2bf(v0[0]); pk[1] = (short)f2bf(v0[1]);
  pk[2] = (short)f2bf(v0[2]); pk[3] = (short)f2bf(v0[3]);
  pk[4] = (short)f2bf(v1[0]); pk[5] = (short)f2bf(v1[1]);
  pk[6] = (short)f2bf(v1[2]); pk[7] = (short)f2bf(v1[3]);
  *(short8*)(xb + e) = pk;
}

// one block per oc row: coalesced f32x4 read -> LDS bf16 -> coalesced write
__global__ __launch_bounds__(256)
void k_convw_out(const float* __restrict__ Wout,
                 unsigned short* __restrict__ out) {
  __shared__ unsigned short row_l[20480];
  const int oc = blockIdx.x;
  const int tid = threadIdx.x;
  const float* src = Wout + (size_t)oc * 20480;
#pragma unroll
  for (int i0 = 0; i0 < 5120; i0 += 256) {  // 20 rounds of f32x4
    int i = i0 + tid;
    f32x4 v = *(const f32x4*)(src + (size_t)i * 4);
    short4v pk;
    pk[0] = (short)f2bf(v[0]); pk[1] = (short)f2bf(v[1]);
    pk[2] = (short)f2bf(v[2]); pk[3] = (short)f2bf(v[3]);
    *(short4v*)(row_l + i * 4) = pk;
  }
  __syncthreads();
  unsigned short* drow = out + (size_t)oc * 20480;
#pragma unroll
  for (int r0 = 0; r0 < 20480; r0 += 512) {  // 40 rounds of ushort2
    int e = r0 + tid * 2;
    int t0 = e >> 12, ft0 = e & 4095;
    int t1 = (e + 1) >> 12, ft1 = (e + 1) & 4095;
    short2v pk;
    pk[0] = (short)row_l[(ft0 >> 3) * 40 + (ft0 & 7) * 5 + t0];
    pk[1] = (short)row_l[(ft1 >> 3) * 40 + (ft1 & 7) * 5 + t1];
    *(short2v*)(drow + e) = pk;
  }
}

// ---------------- K1: qkv conv as GEMM (M=128pos x N=128oc, K=640) ----------------
__global__ __launch_bounds__(256, 2)
void k_qkv(const unsigned short* __restrict__ xb,
           const unsigned short* __restrict__ Wb,
           unsigned short* __restrict__ Qg, unsigned short* __restrict__ Kg,
           unsigned short* __restrict__ Vg) {
  __shared__ __align__(16) unsigned short As[128 * 64];
  __shared__ __align__(16) unsigned short Bs[128 * 64];
  const int tid = threadIdx.x;
  const int lane = tid & 63, w = tid >> 6;
  const int wr = w >> 1, wc = w & 1;
  const int l15 = lane & 15, lg = lane >> 4;
  const int p0 = blockIdx.x * 128;
  const int ocb = blockIdx.y * 128;
  const int m = blockIdx.z;

  f32x4 acc[4][4];
#pragma unroll
  for (int i = 0; i < 4; i++)
#pragma unroll
    for (int j = 0; j < 4; j++) acc[i][j] = (f32x4){0.f, 0.f, 0.f, 0.f};

  for (int ks = 0; ks < 10; ks++) {
    const int t = ks >> 1;
    const int ci0 = (ks & 1) << 6;
    __syncthreads();
    // stage A: im2col 128 pos x 64 ci from xb, 8x16B chunks, chunk^=(row&7)
#pragma unroll
    for (int i = 0; i < 4; i++) {
      int s = tid + (i << 8);
      int row = s >> 3, c = s & 7;
      int cs = c ^ (row & 7);
      int xn = refl4096(p0 + row - 2 + t);
      gl_lds16(xb + (((size_t)xn << 3) + m) * 128 + ci0 + (cs << 3),
               (char*)As + (size_t)s * 16);
    }
    // stage B: bf16 weights straight to LDS (inverse-swizzled source)
#pragma unroll
    for (int c = 0; c < 4; c++) {
      int sb = ((c << 2) + w) << 6;
      int slot = sb + lane;
      int row = slot >> 3, cc = slot & 7;
      int cs = cc ^ (row & 7);
      gl_lds16(Wb + (size_t)(ocb + row) * 640 + (ks << 6) + (cs << 3),
               (char*)Bs + (size_t)sb * 16);
    }
    __syncthreads();
#pragma unroll
    for (int kk = 0; kk < 2; kk++) {
      short8 af[4], bq[4];
#pragma unroll
      for (int i = 0; i < 4; i++) {
        int row = (wr << 6) + (i << 4) + l15;
        af[i] = *(const short8*)((char*)As + (row << 7) +
                                 ((((kk << 2) + lg) ^ (row & 7)) << 4));
      }
#pragma unroll
      for (int j = 0; j < 4; j++) {
        int row = (wc << 6) + (j << 4) + l15;
        bq[j] = *(const short8*)((char*)Bs + (row << 7) +
                                 ((((kk << 2) + lg) ^ (row & 7)) << 4));
      }
#pragma unroll
      for (int i = 0; i < 4; i++)
#pragma unroll
        for (int j = 0; j < 4; j++) acc[i][j] = mfma16(af[i], bq[j], acc[i][j]);
    }
  }

  const int region = ocb >> 9;  // 0:Q 1:K 2:V
  const float QSCALE = 0.18033688f;  // 1/8 * log2(e)
#pragma unroll
  for (int i = 0; i < 4; i++) {
    const int posb = p0 + (wr << 6) + (i << 4) + (lg << 2);
#pragma unroll
    for (int j = 0; j < 4; j++) {
      const int oc = ocb + (wc << 6) + (j << 4) + l15;
      const int ocr = oc & 511;
      const int hh = ocr >> 6, dd = ocr & 63;
      const int f = (dd << 3) + m;
      if (region == 0) {
        size_t base = (size_t)hh * 4096 * 512 + f;
#pragma unroll
        for (int r = 0; r < 4; r++)
          Qg[base + (size_t)(posb + r) * 512] = f2bf(acc[i][j][r] * QSCALE);
      } else if (region == 1) {
        size_t base = (size_t)hh * 4096 * 512 + f;
#pragma unroll
        for (int r = 0; r < 4; r++)
          Kg[base + (size_t)(posb + r) * 512] = f2bf(acc[i][j][r]);
      } else {
        short4v pk;
#pragma unroll
        for (int r = 0; r < 4; r++) pk[r] = (short)f2bf(acc[i][j][r]);
        *(short4v*)(Vg + ((size_t)hh * 512 + f) * 4096 + posb) = pk;
      }
    }
  }
}

// ---------------- K2: flash attention, 8 waves = 4 pairs x 32 q, f-split ----------
// R12: V direct from L2 (no Vt). K double-buffered, staged at B1. Per iter:
//   B1 (drains stageK(t) from last iter) -> stageK(t+1)->Ktn -> QK^T(Ktc)
//   -> Sx -> B2 -> exchange/exp/pack -> PV with direct global V loads
//   (issued after stageK but stageK completed by B2 -> transitive wait free).
__global__ __launch_bounds__(512, 2)
void k_attn(const unsigned short* __restrict__ Qg,
            const unsigned short* __restrict__ Kg,
            const unsigned short* __restrict__ Vg,
            unsigned short* __restrict__ AO) {
  // Kt0 [0,32K) | Kt1 [32K,64K) | Sx [64K,96K) | Ls 512B
  __shared__ __align__(16) char lds[98816];
  char* Kt0 = lds;
  char* Kt1 = lds + 32768;
  char* Sx = lds + 65536;
  float* Ls = (float*)(lds + 98304);

  const int tid = threadIdx.x;
  const int lane = tid & 63, w = tid >> 6;
  const int l31 = lane & 31, hi = lane >> 5;
  const int wpair = w >> 1, whalf = w & 1;
  const int h = blockIdx.x & 7;          // XCD-pinned head
  const int qblk = blockIdx.x >> 3;
  const int qbase = qblk * 128 + wpair * 32;
  const int fh = whalf << 8;  // 0 or 256

  const size_t kb = (size_t)h * 4096 * 512;
  const size_t vb = (size_t)h * 512 * 4096;

  short8 q[16];
  {
    const unsigned short* qp =
        Qg + ((size_t)h * 4096 + qbase + l31) * 512 + fh + hi * 8;
#pragma unroll
    for (int ks = 0; ks < 16; ks++) q[ks] = *(const short8*)(qp + ks * 16);
  }

  f32x16 o[8];
#pragma unroll
  for (int t = 0; t < 8; t++)
#pragma unroll
    for (int e = 0; e < 16; e++) o[t][e] = 0.f;
  float lacc = 0.f;

  // per-lane V base (ushort units): f = whalf*256 + l31 (+32 per f-tile)
  const unsigned short* vlane =
      Vg + vb + (size_t)((whalf << 8) + l31) * 4096 + (hi << 3);

  // Sx: byte = j*8192 + w*1024 + lane*16 (conflict-free b128)
  char* sxw = Sx + (w << 10) + (lane << 4);
  char* sxp = Sx + ((w ^ 1) << 10) + (lane << 4);

  union U { uint32_t d[4]; short8 s; };

  auto stageK = [&](int it, char* Kt) {
    const int key0 = it << 5;
#pragma unroll
    for (int i = 0; i < 4; i++) {
      int s = tid + (i << 9);
      int r = s >> 6, c = s & 63;
      gl_lds16(Kg + kb + (size_t)(key0 + r) * 512 + ((c ^ r) << 3),
               Kt + (size_t)s * 16);
    }
  };

  stageK(0, Kt0);

  for (int it = 0; it < 128; it++) {
    const int key0 = it << 5;
    char* Ktc = (it & 1) ? Kt1 : Kt0;
    char* Ktn = (it & 1) ? Kt0 : Kt1;
    __syncthreads();  // B1: stageK(it) landed; Sx/K readers of last iter done

    if (it < 127) stageK(it + 1, Ktn);  // flies under QK^T; done by ~B2

    f32x16 st;
#pragma unroll
    for (int e = 0; e < 16; e++) st[e] = 0.f;
#pragma unroll
    for (int ks = 0; ks < 16; ks++) {
      int ch = ((fh >> 3) + (ks << 1) + hi) ^ l31;
      short8 kfrag = *(const short8*)(Ktc + (l31 << 10) + (ch << 4));
      st = mfma32(kfrag, q[ks], st);
    }
#pragma unroll
    for (int j = 0; j < 4; j++) {
      f32x4 pw = (f32x4){st[4 * j], st[4 * j + 1], st[4 * j + 2], st[4 * j + 3]};
      *(f32x4*)(sxw + (j << 13)) = pw;
    }
    __syncthreads();  // B2: Ktc reads done, partials visible

#pragma unroll
    for (int j = 0; j < 4; j++) {
      f32x4 pv = *(const f32x4*)(sxp + (j << 13));
      st[4 * j] += pv[0]; st[4 * j + 1] += pv[1];
      st[4 * j + 2] += pv[2]; st[4 * j + 3] += pv[3];
    }

    float p[16];
#pragma unroll
    for (int r = 0; r < 16; r++) p[r] = __builtin_amdgcn_exp2f(st[r]);
    lacc += ((p[0] + p[1]) + (p[2] + p[3])) + ((p[4] + p[5]) + (p[6] + p[7])) +
            (((p[8] + p[9]) + (p[10] + p[11])) +
             ((p[12] + p[13]) + (p[14] + p[15])));

    uint32_t d0 = cvtpk(p[0], p[1]),  d1 = cvtpk(p[2], p[3]);
    uint32_t d2 = cvtpk(p[4], p[5]),  d3 = cvtpk(p[6], p[7]);
    uint32_t d4 = cvtpk(p[8], p[9]),  d5 = cvtpk(p[10], p[11]);
    uint32_t d6 = cvtpk(p[12], p[13]), d7 = cvtpk(p[14], p[15]);
    plswap(d0, d2); plswap(d1, d3);
    plswap(d4, d6); plswap(d5, d7);
    U u1; u1.d[0] = d0; u1.d[1] = d1; u1.d[2] = d2; u1.d[3] = d3;
    U u2; u2.d[0] = d4; u2.d[1] = d5; u2.d[2] = d6; u2.d[3] = d7;

    // O += P · V, V frags direct from L2 (16B contiguous per lane);
    // compiler hoists loads ahead with counted vmcnt (stageK is older &
    // already complete -> no prefetch drain).
    const unsigned short* vp = vlane + key0;
#pragma unroll
    for (int tt = 0; tt < 8; tt++) {
      short8 v1 = *(const short8*)(vp + (size_t)tt * 131072);
      short8 v2 = *(const short8*)(vp + (size_t)tt * 131072 + 16);
      o[tt] = mfma32(u1.s, v1, o[tt]);
      o[tt] = mfma32(u2.s, v2, o[tt]);
    }
  }

  lacc += __shfl_xor(lacc, 32, 64);
  if (whalf == 0) Ls[(wpair << 5) + l31] = lacc;
  __syncthreads();

  float linv[16];
#pragma unroll
  for (int r = 0; r < 16; r++) {
    int qq = (r & 3) + ((r >> 2) << 3) + (hi << 2);
    linv[r] = 1.f / Ls[(wpair << 5) + qq];
  }
#pragma unroll
  for (int tt = 0; tt < 8; tt++) {
    size_t col = (size_t)h * 512 + (((whalf << 3) + tt) << 5) + l31;
#pragma unroll
    for (int r = 0; r < 16; r++) {
      int qq = qbase + (r & 3) + ((r >> 2) << 3) + (hi << 2);
      AO[(size_t)qq * 4096 + col] = f2bf(o[tt][r] * linv[r]);
    }
  }
}

// ---------------- K3: out conv as GEMM (M=128 x N=128, K=20480, BK=64) -----------
// R12: W-frags global->reg, ISSUED BEFORE stageA (vmcnt FIFO: consuming them
// leaves the newer stageA prefetch in flight). Bs removed; A dbuf in LDS.
// W reads are XCD-L2-resident (ocb pinned) and L1-broadcast across wr-waves.
__global__ __launch_bounds__(512, 2)
void k_outconv(const unsigned short* __restrict__ AO,
               const unsigned short* __restrict__ WB,
               float* __restrict__ outp, int b) {
  __shared__ __align__(16) unsigned short As[2][8192];
  const int tid = threadIdx.x;
  const int lane = tid & 63, w = tid >> 6;
  const int wr = w >> 1, wc = w & 1;  // 4 M-bands x 2 N-bands
  const int l15 = lane & 15, lg = lane >> 4;
  const int i0 = (blockIdx.x >> 3) * 128;
  const int ocb = (blockIdx.x & 7) * 128;  // XCD-pinned B panel

  f32x4 acc[2][4];
#pragma unroll
  for (int i = 0; i < 2; i++)
#pragma unroll
    for (int j = 0; j < 4; j++) acc[i][j] = (f32x4){0.f, 0.f, 0.f, 0.f};

  // W source base (ushort units) per (kk,j): row*20480 + kk*32 + lg*8
  const unsigned short* wbase[2][4];
#pragma unroll
  for (int kk = 0; kk < 2; kk++)
#pragma unroll
    for (int j = 0; j < 4; j++)
      wbase[kk][j] = WB +
          (size_t)(ocb + (wc << 6) + (j << 4) + l15) * 20480 +
          (kk << 5) + (lg << 3);

  auto stageA = [&](int ks, int d) {
    const int t = ks >> 6;
    const int f0 = (ks & 63) << 6;
#pragma unroll
    for (int i = 0; i < 2; i++) {  // A: 1024 slots
      int s = tid + (i << 9);
      int row = s >> 3, c = s & 7;
      int cs = c ^ (row & 7);
      int sr = refl4096(i0 + row + t - 2);
      gl_lds16(AO + (size_t)sr * 4096 + f0 + (cs << 3),
               (char*)As[d] + (size_t)s * 16);
    }
  };

  stageA(0, 0);

  for (int ks = 0; ks < 320; ks++) {
    const int d = ks & 1;
    const int k0 = ks << 6;
    __syncthreads();  // A(ks) landed; all waves done with As[d^1]

    // W loads FIRST (older than stageA in vmcnt FIFO)
    short8 wf[2][4];
#pragma unroll
    for (int kk = 0; kk < 2; kk++)
#pragma unroll
      for (int j = 0; j < 4; j++)
        wf[kk][j] = *(const short8*)(wbase[kk][j] + k0);

    if (ks < 319) stageA(ks + 1, d ^ 1);  // newer: stays in flight

#pragma unroll
    for (int kk = 0; kk < 2; kk++) {
      short8 af[2];
#pragma unroll
      for (int i = 0; i < 2; i++) {
        int row = (wr << 5) + (i << 4) + l15;
        af[i] = *(const short8*)((char*)As[d] + (row << 7) +
                                 ((((kk << 2) + lg) ^ (row & 7)) << 4));
      }
#pragma unroll
      for (int i = 0; i < 2; i++)
#pragma unroll
        for (int j = 0; j < 4; j++)
          acc[i][j] = mfma16(af[i], wf[kk][j], acc[i][j]);
    }
  }
#pragma unroll
  for (int i = 0; i < 2; i++)
#pragma unroll
    for (int j = 0; j < 4; j++) {
      int oc = ocb + (wc << 6) + (j << 4) + l15;
      int pos = i0 + (wr << 5) + (i << 4) + (lg << 2);
      *(f32x4*)(outp + ((size_t)b * 1024 + oc) * 4096 + pos) = acc[i][j];
    }
}

// ---------------- launch ----------------
extern "C" void kernel_launch(void* const* d_in, const int* in_sizes, int n_in,
                              void* d_out, int out_size, void* d_ws,
                              size_t ws_size, hipStream_t stream) {
  const float* x = (const float*)d_in[0];
  const float* Wq = (const float*)d_in[1];
  const float* Wkv = (const float*)d_in[2];
  const float* Wout = (const float*)d_in[3];
  float* out = (float*)d_out;
  char* ws = (char*)d_ws;

  const size_t SEG = 33554432;  // 32 MiB
  unsigned short* Qg = (unsigned short*)ws;
  unsigned short* Kg = (unsigned short*)(ws + SEG);
  unsigned short* Vg = (unsigned short*)(ws + 2 * SEG);
  unsigned short* AO = (unsigned short*)(ws + 3 * SEG);
  unsigned short* xb = AO;  // overlays AO (dead until k_attn writes it)
  unsigned short* WB1 = (unsigned short*)(ws + 4 * SEG);  // 1.97 MB
  unsigned short* WB2 = (unsigned short*)ws;  // overlays Qg/Kg during k_outconv

  k_convw_qkv<<<3840, 256, 0, stream>>>(Wq, Wkv, WB1);
  for (int b = 0; b < 2; b++) {
    k_convx<<<2048, 256, 0, stream>>>(x, xb, b);
    k_qkv<<<dim3(32, 12, 8), 256, 0, stream>>>(xb, WB1, Qg, Kg, Vg);
    k_attn<<<256, 512, 0, stream>>>(Qg, Kg, Vg, AO);
    k_convw_out<<<1024, 256, 0, stream>>>(Wout, WB2);
    k_outconv<<<256, 512, 0, stream>>>(AO, WB2, out, b);
  }
}

// Round 13
// 1602.550 us; speedup vs baseline: 1.8935x; 1.8935x over previous
//
#include <hip/hip_runtime.h>
#include <stdint.h>

// Seq_CNN_Big_Attention: qkv 1x5 conv (reflect pad) -> flash attn (head dim 512)
// -> 8x5 out conv. bf16 MFMA pipeline, per-batch sequential to bound ws.
// R13: revert R12 (fragment-layout reads from global = uncoalesced gather;
//      FETCH 245->676MB. LDS round-trip IS the transpose engine). k_attn = R11.
//      k_outconv: 128x64 tile, grid 512 = 2 blocks/CU (R9-R11 grids were
//      1 block/CU -> barrier/staging stalls unoverlapped). convw_out once
//      if ws_size allows a dedicated WB2 region.
// Workspace: base 130 MB; +41 MB WB2 region if ws_size >= 170 MiB.

typedef __attribute__((ext_vector_type(8))) short short8;
typedef __attribute__((ext_vector_type(4))) short short4v;
typedef __attribute__((ext_vector_type(2))) short short2v;
typedef __attribute__((ext_vector_type(4))) float f32x4;
typedef __attribute__((ext_vector_type(16))) float f32x16;

__device__ __forceinline__ f32x4 mfma16(short8 a, short8 b, f32x4 c) {
  return __builtin_amdgcn_mfma_f32_16x16x32_bf16(a, b, c, 0, 0, 0);
}
__device__ __forceinline__ f32x16 mfma32(short8 a, short8 b, f32x16 c) {
  return __builtin_amdgcn_mfma_f32_32x32x16_bf16(a, b, c, 0, 0, 0);
}

__device__ __forceinline__ unsigned short f2bf(float f) {  // RNE f32->bf16
  union { float f; uint32_t u; } v; v.f = f;
  uint32_t r = (v.u + 0x7fffu + ((v.u >> 16) & 1u)) >> 16;
  return (unsigned short)r;
}

__device__ __forceinline__ uint32_t cvtpk(float lo, float hi) {
  uint32_t r;
  asm volatile("v_cvt_pk_bf16_f32 %0, %1, %2" : "=v"(r) : "v"(lo), "v"(hi));
  return r;
}
__device__ __forceinline__ void plswap(uint32_t& a, uint32_t& b) {
  asm volatile("v_permlane32_swap_b32 %0, %1" : "+v"(a), "+v"(b));
}

__device__ __forceinline__ int refl4096(int p) {  // reflect pad-2 index
  p = p < 0 ? -p : p;
  return p >= 4096 ? 8190 - p : p;
}

__device__ __forceinline__ void gl_lds16(const void* g, void* l) {
  __builtin_amdgcn_global_load_lds(
      (const __attribute__((address_space(1))) void*)g,
      (__attribute__((address_space(3))) void*)l, 16, 0, 0);
}

// ---------------- converters ----------------
__global__ void k_convw_qkv(const float* __restrict__ Wq,
                            const float* __restrict__ Wkv,
                            unsigned short* __restrict__ out) {
  int e = blockIdx.x * 256 + threadIdx.x;  // 1536*640 exact
  int oc = e / 640, k = e - oc * 640;
  int ci = k & 127, t = k >> 7;
  float w = (oc < 512) ? Wq[oc * 640 + ci * 5 + t]
                       : Wkv[(oc - 512) * 640 + ci * 5 + t];
  out[e] = f2bf(w);
}

// x (f32, one batch) -> xb bf16 [n][m][c] contiguous
__global__ __launch_bounds__(256)
void k_convx(const float* __restrict__ x, unsigned short* __restrict__ xb,
             int b) {
  int e = (blockIdx.x * 256 + threadIdx.x) * 8;  // 4194304 per batch
  const float* src = x + (size_t)b * 4194304 + e;
  f32x4 v0 = *(const f32x4*)src;
  f32x4 v1 = *(const f32x4*)(src + 4);
  short8 pk;
  pk[0] = (short)f2bf(v0[0]); pk[1] = (short)f2bf(v0[1]);
  pk[2] = (short)f2bf(v0[2]); pk[3] = (short)f2bf(v0[3]);
  pk[4] = (short)f2bf(v1[0]); pk[5] = (short)f2bf(v1[1]);
  pk[6] = (short)f2bf(v1[2]); pk[7] = (short)f2bf(v1[3]);
  *(short8*)(xb + e) = pk;
}

// one block per oc row: coalesced f32x4 read -> LDS bf16 -> coalesced write
__global__ __launch_bounds__(256)
void k_convw_out(const float* __restrict__ Wout,
                 unsigned short* __restrict__ out) {
  __shared__ unsigned short row_l[20480];
  const int oc = blockIdx.x;
  const int tid = threadIdx.x;
  const float* src = Wout + (size_t)oc * 20480;
#pragma unroll
  for (int i0 = 0; i0 < 5120; i0 += 256) {  // 20 rounds of f32x4
    int i = i0 + tid;
    f32x4 v = *(const f32x4*)(src + (size_t)i * 4);
    short4v pk;
    pk[0] = (short)f2bf(v[0]); pk[1] = (short)f2bf(v[1]);
    pk[2] = (short)f2bf(v[2]); pk[3] = (short)f2bf(v[3]);
    *(short4v*)(row_l + i * 4) = pk;
  }
  __syncthreads();
  unsigned short* drow = out + (size_t)oc * 20480;
#pragma unroll
  for (int r0 = 0; r0 < 20480; r0 += 512) {  // 40 rounds of ushort2
    int e = r0 + tid * 2;
    int t0 = e >> 12, ft0 = e & 4095;
    int t1 = (e + 1) >> 12, ft1 = (e + 1) & 4095;
    short2v pk;
    pk[0] = (short)row_l[(ft0 >> 3) * 40 + (ft0 & 7) * 5 + t0];
    pk[1] = (short)row_l[(ft1 >> 3) * 40 + (ft1 & 7) * 5 + t1];
    *(short2v*)(drow + e) = pk;
  }
}

// ---------------- K1: qkv conv as GEMM (M=128pos x N=128oc, K=640) ----------------
__global__ __launch_bounds__(256, 2)
void k_qkv(const unsigned short* __restrict__ xb,
           const unsigned short* __restrict__ Wb,
           unsigned short* __restrict__ Qg, unsigned short* __restrict__ Kg,
           unsigned short* __restrict__ Vg) {
  __shared__ __align__(16) unsigned short As[128 * 64];
  __shared__ __align__(16) unsigned short Bs[128 * 64];
  const int tid = threadIdx.x;
  const int lane = tid & 63, w = tid >> 6;
  const int wr = w >> 1, wc = w & 1;
  const int l15 = lane & 15, lg = lane >> 4;
  const int p0 = blockIdx.x * 128;
  const int ocb = blockIdx.y * 128;
  const int m = blockIdx.z;

  f32x4 acc[4][4];
#pragma unroll
  for (int i = 0; i < 4; i++)
#pragma unroll
    for (int j = 0; j < 4; j++) acc[i][j] = (f32x4){0.f, 0.f, 0.f, 0.f};

  for (int ks = 0; ks < 10; ks++) {
    const int t = ks >> 1;
    const int ci0 = (ks & 1) << 6;
    __syncthreads();
    // stage A: im2col 128 pos x 64 ci from xb, 8x16B chunks, chunk^=(row&7)
#pragma unroll
    for (int i = 0; i < 4; i++) {
      int s = tid + (i << 8);
      int row = s >> 3, c = s & 7;
      int cs = c ^ (row & 7);
      int xn = refl4096(p0 + row - 2 + t);
      gl_lds16(xb + (((size_t)xn << 3) + m) * 128 + ci0 + (cs << 3),
               (char*)As + (size_t)s * 16);
    }
    // stage B: bf16 weights straight to LDS (inverse-swizzled source)
#pragma unroll
    for (int c = 0; c < 4; c++) {
      int sb = ((c << 2) + w) << 6;
      int slot = sb + lane;
      int row = slot >> 3, cc = slot & 7;
      int cs = cc ^ (row & 7);
      gl_lds16(Wb + (size_t)(ocb + row) * 640 + (ks << 6) + (cs << 3),
               (char*)Bs + (size_t)sb * 16);
    }
    __syncthreads();
#pragma unroll
    for (int kk = 0; kk < 2; kk++) {
      short8 af[4], bq[4];
#pragma unroll
      for (int i = 0; i < 4; i++) {
        int row = (wr << 6) + (i << 4) + l15;
        af[i] = *(const short8*)((char*)As + (row << 7) +
                                 ((((kk << 2) + lg) ^ (row & 7)) << 4));
      }
#pragma unroll
      for (int j = 0; j < 4; j++) {
        int row = (wc << 6) + (j << 4) + l15;
        bq[j] = *(const short8*)((char*)Bs + (row << 7) +
                                 ((((kk << 2) + lg) ^ (row & 7)) << 4));
      }
#pragma unroll
      for (int i = 0; i < 4; i++)
#pragma unroll
        for (int j = 0; j < 4; j++) acc[i][j] = mfma16(af[i], bq[j], acc[i][j]);
    }
  }

  const int region = ocb >> 9;  // 0:Q 1:K 2:V
  const float QSCALE = 0.18033688f;  // 1/8 * log2(e)
#pragma unroll
  for (int i = 0; i < 4; i++) {
    const int posb = p0 + (wr << 6) + (i << 4) + (lg << 2);
#pragma unroll
    for (int j = 0; j < 4; j++) {
      const int oc = ocb + (wc << 6) + (j << 4) + l15;
      const int ocr = oc & 511;
      const int hh = ocr >> 6, dd = ocr & 63;
      const int f = (dd << 3) + m;
      if (region == 0) {
        size_t base = (size_t)hh * 4096 * 512 + f;
#pragma unroll
        for (int r = 0; r < 4; r++)
          Qg[base + (size_t)(posb + r) * 512] = f2bf(acc[i][j][r] * QSCALE);
      } else if (region == 1) {
        size_t base = (size_t)hh * 4096 * 512 + f;
#pragma unroll
        for (int r = 0; r < 4; r++)
          Kg[base + (size_t)(posb + r) * 512] = f2bf(acc[i][j][r]);
      } else {
        short4v pk;
#pragma unroll
        for (int r = 0; r < 4; r++) pk[r] = (short)f2bf(acc[i][j][r]);
        *(short4v*)(Vg + ((size_t)hh * 512 + f) * 4096 + posb) = pk;
      }
    }
  }
}

// ---------------- K2: flash attention (R11 form), 8 waves = 4 pairs x 32 q --------
__global__ __launch_bounds__(512, 2)
void k_attn(const unsigned short* __restrict__ Qg,
            const unsigned short* __restrict__ Kg,
            const unsigned short* __restrict__ Vg,
            unsigned short* __restrict__ AO) {
  // Kt [0,32K) | Vt0 [32K,64K) | Vt1 [64K,96K) | Sx [96K,128K) | Ls 512B
  __shared__ __align__(16) char lds[131584];
  char* Kt = lds;
  char* Vt0 = lds + 32768;
  char* Vt1 = lds + 65536;
  char* Sx = lds + 98304;
  float* Ls = (float*)(lds + 131072);

  const int tid = threadIdx.x;
  const int lane = tid & 63, w = tid >> 6;
  const int l31 = lane & 31, hi = lane >> 5;
  const int wpair = w >> 1, whalf = w & 1;
  const int h = blockIdx.x & 7;          // XCD-pinned head
  const int qblk = blockIdx.x >> 3;
  const int qbase = qblk * 128 + wpair * 32;
  const int fh = whalf << 8;  // 0 or 256

  const size_t kb = (size_t)h * 4096 * 512;
  const size_t vb = (size_t)h * 512 * 4096;

  short8 q[16];
  {
    const unsigned short* qp =
        Qg + ((size_t)h * 4096 + qbase + l31) * 512 + fh + hi * 8;
#pragma unroll
    for (int ks = 0; ks < 16; ks++) q[ks] = *(const short8*)(qp + ks * 16);
  }

  f32x16 o[8];
#pragma unroll
  for (int t = 0; t < 8; t++)
#pragma unroll
    for (int e = 0; e < 16; e++) o[t][e] = 0.f;
  float lacc = 0.f;

  // PV read constants (R5-verified)
  const int rb = l31 >> 1;
  const int swz = rb & 7;
  const int cg0 = ((l31 & 1) << 2) + hi;
  const int voff1 = rb * 128 + ((cg0 ^ swz) << 4);
  const int voff2 = rb * 128 + (((cg0 + 2) ^ swz) << 4);

  // Sx: byte = j*8192 + w*1024 + lane*16 (conflict-free b128)
  char* sxw = Sx + (w << 10) + (lane << 4);
  char* sxp = Sx + ((w ^ 1) << 10) + (lane << 4);

  union U { uint32_t d[4]; short8 s; };

  auto stageK = [&](int it) {
    const int key0 = it << 5;
#pragma unroll
    for (int i = 0; i < 4; i++) {
      int s = tid + (i << 9);
      int r = s >> 6, c = s & 63;
      gl_lds16(Kg + kb + (size_t)(key0 + r) * 512 + ((c ^ r) << 3),
               Kt + (size_t)s * 16);
    }
  };
  auto stageV = [&](int it, char* Vt) {
    const int key0 = it << 5;
#pragma unroll
    for (int i = 0; i < 4; i++) {
      int s = tid + (i << 9);
      int rp = s >> 3, c = s & 7;
      int cu = c ^ (rp & 7);
      int f = (rp << 1) + (cu >> 2);
      gl_lds16(Vg + vb + (size_t)f * 4096 + key0 + ((cu & 3) << 3),
               Vt + (size_t)s * 16);
    }
  };

  stageK(0);
  stageV(0, Vt0);

  for (int it = 0; it < 128; it++) {
    char* Vt = (it & 1) ? Vt1 : Vt0;
    char* Vn = (it & 1) ? Vt0 : Vt1;
    __syncthreads();  // B1: staged tiles landed

    if (it < 127) stageV(it + 1, Vn);  // flies under QK^T + Sx + B2

    f32x16 st;
#pragma unroll
    for (int e = 0; e < 16; e++) st[e] = 0.f;
#pragma unroll
    for (int ks = 0; ks < 16; ks++) {
      int ch = ((fh >> 3) + (ks << 1) + hi) ^ l31;
      short8 kfrag = *(const short8*)(Kt + (l31 << 10) + (ch << 4));
      st = mfma32(kfrag, q[ks], st);
    }
#pragma unroll
    for (int j = 0; j < 4; j++) {
      f32x4 pw = (f32x4){st[4 * j], st[4 * j + 1], st[4 * j + 2], st[4 * j + 3]};
      *(f32x4*)(sxw + (j << 13)) = pw;
    }
    __syncthreads();  // B2: Kt reads done, partials visible

    if (it < 127) stageK(it + 1);

#pragma unroll
    for (int j = 0; j < 4; j++) {
      f32x4 pv = *(const f32x4*)(sxp + (j << 13));
      st[4 * j] += pv[0]; st[4 * j + 1] += pv[1];
      st[4 * j + 2] += pv[2]; st[4 * j + 3] += pv[3];
    }

    float p[16];
#pragma unroll
    for (int r = 0; r < 16; r++) p[r] = __builtin_amdgcn_exp2f(st[r]);
    lacc += ((p[0] + p[1]) + (p[2] + p[3])) + ((p[4] + p[5]) + (p[6] + p[7])) +
            (((p[8] + p[9]) + (p[10] + p[11])) +
             ((p[12] + p[13]) + (p[14] + p[15])));

    uint32_t d0 = cvtpk(p[0], p[1]),  d1 = cvtpk(p[2], p[3]);
    uint32_t d2 = cvtpk(p[4], p[5]),  d3 = cvtpk(p[6], p[7]);
    uint32_t d4 = cvtpk(p[8], p[9]),  d5 = cvtpk(p[10], p[11]);
    uint32_t d6 = cvtpk(p[12], p[13]), d7 = cvtpk(p[14], p[15]);
    plswap(d0, d2); plswap(d1, d3);
    plswap(d4, d6); plswap(d5, d7);
    U u1; u1.d[0] = d0; u1.d[1] = d1; u1.d[2] = d2; u1.d[3] = d3;
    U u2; u2.d[0] = d4; u2.d[1] = d5; u2.d[2] = d6; u2.d[3] = d7;

#pragma unroll
    for (int tt = 0; tt < 8; tt++) {
      const char* vrow = Vt + (((whalf << 3) + tt) << 11);
      short8 v1 = *(const short8*)(vrow + voff1);
      short8 v2 = *(const short8*)(vrow + voff2);
      o[tt] = mfma32(u1.s, v1, o[tt]);
      o[tt] = mfma32(u2.s, v2, o[tt]);
    }
  }

  lacc += __shfl_xor(lacc, 32, 64);
  if (whalf == 0) Ls[(wpair << 5) + l31] = lacc;
  __syncthreads();

  float linv[16];
#pragma unroll
  for (int r = 0; r < 16; r++) {
    int qq = (r & 3) + ((r >> 2) << 3) + (hi << 2);
    linv[r] = 1.f / Ls[(wpair << 5) + qq];
  }
#pragma unroll
  for (int tt = 0; tt < 8; tt++) {
    size_t col = (size_t)h * 512 + (((whalf << 3) + tt) << 5) + l31;
#pragma unroll
    for (int r = 0; r < 16; r++) {
      int qq = qbase + (r & 3) + ((r >> 2) << 3) + (hi << 2);
      AO[(size_t)qq * 4096 + col] = f2bf(o[tt][r] * linv[r]);
    }
  }
}

// ---------------- K3: out conv as GEMM (M=128 x N=64, K=20480, BK=64) ------------
// Grid 512 = 2 blocks/CU (R9-R11 were grid-capped at 1 block/CU). 256 thr,
// 4 waves, wave tile 64x32. Conflict-free chunk^(row&7) layout + 1-barrier
// dbuf prefetch. B panel = (bid&15)*64 -> 2 panels per XCD (L2-streamed).
__global__ __launch_bounds__(256, 2)
void k_outconv(const unsigned short* __restrict__ AO,
               const unsigned short* __restrict__ WB,
               float* __restrict__ outp, int b) {
  __shared__ __align__(16) unsigned short As[2][8192];  // 16 KB each
  __shared__ __align__(16) unsigned short Bs[2][4096];  //  8 KB each
  const int tid = threadIdx.x;
  const int lane = tid & 63, w = tid >> 6;
  const int wr = w >> 1, wc = w & 1;  // 2 M-bands x 2 N-bands
  const int l15 = lane & 15, lg = lane >> 4;
  const int i0 = (blockIdx.x >> 4) * 128;
  const int ocb = (blockIdx.x & 15) * 64;

  f32x4 acc[4][2];
#pragma unroll
  for (int i = 0; i < 4; i++)
#pragma unroll
    for (int j = 0; j < 2; j++) acc[i][j] = (f32x4){0.f, 0.f, 0.f, 0.f};

  auto stage = [&](int ks, int d) {
    const int t = ks >> 6;
    const int f0 = (ks & 63) << 6;
    const int k0 = ks << 6;
#pragma unroll
    for (int i = 0; i < 4; i++) {  // A: 1024 slots (128 rows x 8 chunks)
      int s = tid + (i << 8);
      int row = s >> 3, c = s & 7;
      int cs = c ^ (row & 7);
      int sr = refl4096(i0 + row + t - 2);
      gl_lds16(AO + (size_t)sr * 4096 + f0 + (cs << 3),
               (char*)As[d] + (size_t)s * 16);
    }
#pragma unroll
    for (int i = 0; i < 2; i++) {  // B: 512 slots (64 rows x 8 chunks)
      int s = tid + (i << 8);
      int row = s >> 3, c = s & 7;
      int cs = c ^ (row & 7);
      gl_lds16(WB + (size_t)(ocb + row) * 20480 + k0 + (cs << 3),
               (char*)Bs[d] + (size_t)s * 16);
    }
  };

  stage(0, 0);

  for (int ks = 0; ks < 320; ks++) {
    const int d = ks & 1;
    __syncthreads();  // buf[d] staged loads landed; all waves done with buf[d^1]
    if (ks < 319) stage(ks + 1, d ^ 1);
#pragma unroll
    for (int kk = 0; kk < 2; kk++) {
      short8 af[4], bq[2];
#pragma unroll
      for (int i = 0; i < 4; i++) {
        int row = (wr << 6) + (i << 4) + l15;
        af[i] = *(const short8*)((char*)As[d] + (row << 7) +
                                 ((((kk << 2) + lg) ^ (row & 7)) << 4));
      }
#pragma unroll
      for (int j = 0; j < 2; j++) {
        int row = (wc << 5) + (j << 4) + l15;
        bq[j] = *(const short8*)((char*)Bs[d] + (row << 7) +
                                 ((((kk << 2) + lg) ^ (row & 7)) << 4));
      }
#pragma unroll
      for (int i = 0; i < 4; i++)
#pragma unroll
        for (int j = 0; j < 2; j++) acc[i][j] = mfma16(af[i], bq[j], acc[i][j]);
    }
  }
#pragma unroll
  for (int i = 0; i < 4; i++)
#pragma unroll
    for (int j = 0; j < 2; j++) {
      int oc = ocb + (wc << 5) + (j << 4) + l15;
      int pos = i0 + (wr << 6) + (i << 4) + (lg << 2);
      *(f32x4*)(outp + ((size_t)b * 1024 + oc) * 4096 + pos) = acc[i][j];
    }
}

// ---------------- launch ----------------
extern "C" void kernel_launch(void* const* d_in, const int* in_sizes, int n_in,
                              void* d_out, int out_size, void* d_ws,
                              size_t ws_size, hipStream_t stream) {
  const float* x = (const float*)d_in[0];
  const float* Wq = (const float*)d_in[1];
  const float* Wkv = (const float*)d_in[2];
  const float* Wout = (const float*)d_in[3];
  float* out = (float*)d_out;
  char* ws = (char*)d_ws;

  const size_t SEG = 33554432;  // 32 MiB
  unsigned short* Qg = (unsigned short*)ws;
  unsigned short* Kg = (unsigned short*)(ws + SEG);
  unsigned short* Vg = (unsigned short*)(ws + 2 * SEG);
  unsigned short* AO = (unsigned short*)(ws + 3 * SEG);
  unsigned short* xb = AO;  // overlays AO (dead until k_attn writes it)
  unsigned short* WB1 = (unsigned short*)(ws + 4 * SEG);  // ends at 136,183,808

  // WB2: dedicated region if ws allows (convert Wout once); else overlay Qg/Kg
  // and reconvert per batch.
  const size_t WB2_OFF = 136183808;               // WB1 end, 16B-aligned
  const size_t WB2_BYTES = (size_t)1024 * 20480 * 2;
  const bool wb2_once = ws_size >= WB2_OFF + WB2_BYTES;
  unsigned short* WB2 =
      wb2_once ? (unsigned short*)(ws + WB2_OFF) : (unsigned short*)ws;

  k_convw_qkv<<<3840, 256, 0, stream>>>(Wq, Wkv, WB1);
  if (wb2_once) k_convw_out<<<1024, 256, 0, stream>>>(Wout, WB2);
  for (int b = 0; b < 2; b++) {
    k_convx<<<2048, 256, 0, stream>>>(x, xb, b);
    k_qkv<<<dim3(32, 12, 8), 256, 0, stream>>>(xb, WB1, Qg, Kg, Vg);
    k_attn<<<256, 512, 0, stream>>>(Qg, Kg, Vg, AO);
    if (!wb2_once) k_convw_out<<<1024, 256, 0, stream>>>(Wout, WB2);
    k_outconv<<<512, 256, 0, stream>>>(AO, WB2, out, b);
  }
}

// Round 14
// 1414.923 us; speedup vs baseline: 2.1446x; 1.1326x over previous
//
#include <hip/hip_runtime.h>
#include <stdint.h>

// Seq_CNN_Big_Attention: qkv 1x5 conv (reflect pad) -> flash attn (head dim 512)
// -> 8x5 out conv. bf16 MFMA pipeline, per-batch sequential to bound ws.
// R14: k_outconv split-K: (128,128) tile (fetch-optimal with XCD-pinned B:
//      FETCH ~ 32MB x (1024/N)) x 2 K-slices -> grid 512 = 2 blocks/CU
//      (R9-R11 were grid-capped at 1). f32 partials in dead Vg region (32MiB),
//      k_reduce sums. k_attn / k_qkv unchanged from R13.
// Workspace: base 130 MB; +41 MB WB2 region if ws_size >= 177 MB.
//   Partials P[2][1024][4096] f32 overlay Vg (dead during k_outconv).

typedef __attribute__((ext_vector_type(8))) short short8;
typedef __attribute__((ext_vector_type(4))) short short4v;
typedef __attribute__((ext_vector_type(2))) short short2v;
typedef __attribute__((ext_vector_type(4))) float f32x4;
typedef __attribute__((ext_vector_type(16))) float f32x16;

__device__ __forceinline__ f32x4 mfma16(short8 a, short8 b, f32x4 c) {
  return __builtin_amdgcn_mfma_f32_16x16x32_bf16(a, b, c, 0, 0, 0);
}
__device__ __forceinline__ f32x16 mfma32(short8 a, short8 b, f32x16 c) {
  return __builtin_amdgcn_mfma_f32_32x32x16_bf16(a, b, c, 0, 0, 0);
}

__device__ __forceinline__ unsigned short f2bf(float f) {  // RNE f32->bf16
  union { float f; uint32_t u; } v; v.f = f;
  uint32_t r = (v.u + 0x7fffu + ((v.u >> 16) & 1u)) >> 16;
  return (unsigned short)r;
}

__device__ __forceinline__ uint32_t cvtpk(float lo, float hi) {
  uint32_t r;
  asm volatile("v_cvt_pk_bf16_f32 %0, %1, %2" : "=v"(r) : "v"(lo), "v"(hi));
  return r;
}
__device__ __forceinline__ void plswap(uint32_t& a, uint32_t& b) {
  asm volatile("v_permlane32_swap_b32 %0, %1" : "+v"(a), "+v"(b));
}

__device__ __forceinline__ int refl4096(int p) {  // reflect pad-2 index
  p = p < 0 ? -p : p;
  return p >= 4096 ? 8190 - p : p;
}

__device__ __forceinline__ void gl_lds16(const void* g, void* l) {
  __builtin_amdgcn_global_load_lds(
      (const __attribute__((address_space(1))) void*)g,
      (__attribute__((address_space(3))) void*)l, 16, 0, 0);
}

// ---------------- converters ----------------
__global__ void k_convw_qkv(const float* __restrict__ Wq,
                            const float* __restrict__ Wkv,
                            unsigned short* __restrict__ out) {
  int e = blockIdx.x * 256 + threadIdx.x;  // 1536*640 exact
  int oc = e / 640, k = e - oc * 640;
  int ci = k & 127, t = k >> 7;
  float w = (oc < 512) ? Wq[oc * 640 + ci * 5 + t]
                       : Wkv[(oc - 512) * 640 + ci * 5 + t];
  out[e] = f2bf(w);
}

// x (f32, one batch) -> xb bf16 [n][m][c] contiguous
__global__ __launch_bounds__(256)
void k_convx(const float* __restrict__ x, unsigned short* __restrict__ xb,
             int b) {
  int e = (blockIdx.x * 256 + threadIdx.x) * 8;  // 4194304 per batch
  const float* src = x + (size_t)b * 4194304 + e;
  f32x4 v0 = *(const f32x4*)src;
  f32x4 v1 = *(const f32x4*)(src + 4);
  short8 pk;
  pk[0] = (short)f2bf(v0[0]); pk[1] = (short)f2bf(v0[1]);
  pk[2] = (short)f2bf(v0[2]); pk[3] = (short)f2bf(v0[3]);
  pk[4] = (short)f2bf(v1[0]); pk[5] = (short)f2bf(v1[1]);
  pk[6] = (short)f2bf(v1[2]); pk[7] = (short)f2bf(v1[3]);
  *(short8*)(xb + e) = pk;
}

// one block per oc row: coalesced f32x4 read -> LDS bf16 -> coalesced write
__global__ __launch_bounds__(256)
void k_convw_out(const float* __restrict__ Wout,
                 unsigned short* __restrict__ out) {
  __shared__ unsigned short row_l[20480];
  const int oc = blockIdx.x;
  const int tid = threadIdx.x;
  const float* src = Wout + (size_t)oc * 20480;
#pragma unroll
  for (int i0 = 0; i0 < 5120; i0 += 256) {  // 20 rounds of f32x4
    int i = i0 + tid;
    f32x4 v = *(const f32x4*)(src + (size_t)i * 4);
    short4v pk;
    pk[0] = (short)f2bf(v[0]); pk[1] = (short)f2bf(v[1]);
    pk[2] = (short)f2bf(v[2]); pk[3] = (short)f2bf(v[3]);
    *(short4v*)(row_l + i * 4) = pk;
  }
  __syncthreads();
  unsigned short* drow = out + (size_t)oc * 20480;
#pragma unroll
  for (int r0 = 0; r0 < 20480; r0 += 512) {  // 40 rounds of ushort2
    int e = r0 + tid * 2;
    int t0 = e >> 12, ft0 = e & 4095;
    int t1 = (e + 1) >> 12, ft1 = (e + 1) & 4095;
    short2v pk;
    pk[0] = (short)row_l[(ft0 >> 3) * 40 + (ft0 & 7) * 5 + t0];
    pk[1] = (short)row_l[(ft1 >> 3) * 40 + (ft1 & 7) * 5 + t1];
    *(short2v*)(drow + e) = pk;
  }
}

// partial sum: out[b] = P[0] + P[1]
__global__ __launch_bounds__(256)
void k_reduce(const float* __restrict__ P, float* __restrict__ outp, int b) {
  int e = (blockIdx.x * 256 + threadIdx.x) * 4;  // 4194304 elements
  f32x4 a = *(const f32x4*)(P + e);
  f32x4 c = *(const f32x4*)(P + 4194304 + e);
  f32x4 s = (f32x4){a[0] + c[0], a[1] + c[1], a[2] + c[2], a[3] + c[3]};
  *(f32x4*)(outp + (size_t)b * 4194304 + e) = s;
}

// ---------------- K1: qkv conv as GEMM (M=128pos x N=128oc, K=640) ----------------
__global__ __launch_bounds__(256, 2)
void k_qkv(const unsigned short* __restrict__ xb,
           const unsigned short* __restrict__ Wb,
           unsigned short* __restrict__ Qg, unsigned short* __restrict__ Kg,
           unsigned short* __restrict__ Vg) {
  __shared__ __align__(16) unsigned short As[128 * 64];
  __shared__ __align__(16) unsigned short Bs[128 * 64];
  const int tid = threadIdx.x;
  const int lane = tid & 63, w = tid >> 6;
  const int wr = w >> 1, wc = w & 1;
  const int l15 = lane & 15, lg = lane >> 4;
  const int p0 = blockIdx.x * 128;
  const int ocb = blockIdx.y * 128;
  const int m = blockIdx.z;

  f32x4 acc[4][4];
#pragma unroll
  for (int i = 0; i < 4; i++)
#pragma unroll
    for (int j = 0; j < 4; j++) acc[i][j] = (f32x4){0.f, 0.f, 0.f, 0.f};

  for (int ks = 0; ks < 10; ks++) {
    const int t = ks >> 1;
    const int ci0 = (ks & 1) << 6;
    __syncthreads();
    // stage A: im2col 128 pos x 64 ci from xb, 8x16B chunks, chunk^=(row&7)
#pragma unroll
    for (int i = 0; i < 4; i++) {
      int s = tid + (i << 8);
      int row = s >> 3, c = s & 7;
      int cs = c ^ (row & 7);
      int xn = refl4096(p0 + row - 2 + t);
      gl_lds16(xb + (((size_t)xn << 3) + m) * 128 + ci0 + (cs << 3),
               (char*)As + (size_t)s * 16);
    }
    // stage B: bf16 weights straight to LDS (inverse-swizzled source)
#pragma unroll
    for (int c = 0; c < 4; c++) {
      int sb = ((c << 2) + w) << 6;
      int slot = sb + lane;
      int row = slot >> 3, cc = slot & 7;
      int cs = cc ^ (row & 7);
      gl_lds16(Wb + (size_t)(ocb + row) * 640 + (ks << 6) + (cs << 3),
               (char*)Bs + (size_t)sb * 16);
    }
    __syncthreads();
#pragma unroll
    for (int kk = 0; kk < 2; kk++) {
      short8 af[4], bq[4];
#pragma unroll
      for (int i = 0; i < 4; i++) {
        int row = (wr << 6) + (i << 4) + l15;
        af[i] = *(const short8*)((char*)As + (row << 7) +
                                 ((((kk << 2) + lg) ^ (row & 7)) << 4));
      }
#pragma unroll
      for (int j = 0; j < 4; j++) {
        int row = (wc << 6) + (j << 4) + l15;
        bq[j] = *(const short8*)((char*)Bs + (row << 7) +
                                 ((((kk << 2) + lg) ^ (row & 7)) << 4));
      }
#pragma unroll
      for (int i = 0; i < 4; i++)
#pragma unroll
        for (int j = 0; j < 4; j++) acc[i][j] = mfma16(af[i], bq[j], acc[i][j]);
    }
  }

  const int region = ocb >> 9;  // 0:Q 1:K 2:V
  const float QSCALE = 0.18033688f;  // 1/8 * log2(e)
#pragma unroll
  for (int i = 0; i < 4; i++) {
    const int posb = p0 + (wr << 6) + (i << 4) + (lg << 2);
#pragma unroll
    for (int j = 0; j < 4; j++) {
      const int oc = ocb + (wc << 6) + (j << 4) + l15;
      const int ocr = oc & 511;
      const int hh = ocr >> 6, dd = ocr & 63;
      const int f = (dd << 3) + m;
      if (region == 0) {
        size_t base = (size_t)hh * 4096 * 512 + f;
#pragma unroll
        for (int r = 0; r < 4; r++)
          Qg[base + (size_t)(posb + r) * 512] = f2bf(acc[i][j][r] * QSCALE);
      } else if (region == 1) {
        size_t base = (size_t)hh * 4096 * 512 + f;
#pragma unroll
        for (int r = 0; r < 4; r++)
          Kg[base + (size_t)(posb + r) * 512] = f2bf(acc[i][j][r]);
      } else {
        short4v pk;
#pragma unroll
        for (int r = 0; r < 4; r++) pk[r] = (short)f2bf(acc[i][j][r]);
        *(short4v*)(Vg + ((size_t)hh * 512 + f) * 4096 + posb) = pk;
      }
    }
  }
}

// ---------------- K2: flash attention (R11 form), 8 waves = 4 pairs x 32 q --------
__global__ __launch_bounds__(512, 2)
void k_attn(const unsigned short* __restrict__ Qg,
            const unsigned short* __restrict__ Kg,
            const unsigned short* __restrict__ Vg,
            unsigned short* __restrict__ AO) {
  // Kt [0,32K) | Vt0 [32K,64K) | Vt1 [64K,96K) | Sx [96K,128K) | Ls 512B
  __shared__ __align__(16) char lds[131584];
  char* Kt = lds;
  char* Vt0 = lds + 32768;
  char* Vt1 = lds + 65536;
  char* Sx = lds + 98304;
  float* Ls = (float*)(lds + 131072);

  const int tid = threadIdx.x;
  const int lane = tid & 63, w = tid >> 6;
  const int l31 = lane & 31, hi = lane >> 5;
  const int wpair = w >> 1, whalf = w & 1;
  const int h = blockIdx.x & 7;          // XCD-pinned head
  const int qblk = blockIdx.x >> 3;
  const int qbase = qblk * 128 + wpair * 32;
  const int fh = whalf << 8;  // 0 or 256

  const size_t kb = (size_t)h * 4096 * 512;
  const size_t vb = (size_t)h * 512 * 4096;

  short8 q[16];
  {
    const unsigned short* qp =
        Qg + ((size_t)h * 4096 + qbase + l31) * 512 + fh + hi * 8;
#pragma unroll
    for (int ks = 0; ks < 16; ks++) q[ks] = *(const short8*)(qp + ks * 16);
  }

  f32x16 o[8];
#pragma unroll
  for (int t = 0; t < 8; t++)
#pragma unroll
    for (int e = 0; e < 16; e++) o[t][e] = 0.f;
  float lacc = 0.f;

  // PV read constants (R5-verified)
  const int rb = l31 >> 1;
  const int swz = rb & 7;
  const int cg0 = ((l31 & 1) << 2) + hi;
  const int voff1 = rb * 128 + ((cg0 ^ swz) << 4);
  const int voff2 = rb * 128 + (((cg0 + 2) ^ swz) << 4);

  // Sx: byte = j*8192 + w*1024 + lane*16 (conflict-free b128)
  char* sxw = Sx + (w << 10) + (lane << 4);
  char* sxp = Sx + ((w ^ 1) << 10) + (lane << 4);

  union U { uint32_t d[4]; short8 s; };

  auto stageK = [&](int it) {
    const int key0 = it << 5;
#pragma unroll
    for (int i = 0; i < 4; i++) {
      int s = tid + (i << 9);
      int r = s >> 6, c = s & 63;
      gl_lds16(Kg + kb + (size_t)(key0 + r) * 512 + ((c ^ r) << 3),
               Kt + (size_t)s * 16);
    }
  };
  auto stageV = [&](int it, char* Vt) {
    const int key0 = it << 5;
#pragma unroll
    for (int i = 0; i < 4; i++) {
      int s = tid + (i << 9);
      int rp = s >> 3, c = s & 7;
      int cu = c ^ (rp & 7);
      int f = (rp << 1) + (cu >> 2);
      gl_lds16(Vg + vb + (size_t)f * 4096 + key0 + ((cu & 3) << 3),
               Vt + (size_t)s * 16);
    }
  };

  stageK(0);
  stageV(0, Vt0);

  for (int it = 0; it < 128; it++) {
    char* Vt = (it & 1) ? Vt1 : Vt0;
    char* Vn = (it & 1) ? Vt0 : Vt1;
    __syncthreads();  // B1: staged tiles landed

    if (it < 127) stageV(it + 1, Vn);  // flies under QK^T + Sx + B2

    f32x16 st;
#pragma unroll
    for (int e = 0; e < 16; e++) st[e] = 0.f;
#pragma unroll
    for (int ks = 0; ks < 16; ks++) {
      int ch = ((fh >> 3) + (ks << 1) + hi) ^ l31;
      short8 kfrag = *(const short8*)(Kt + (l31 << 10) + (ch << 4));
      st = mfma32(kfrag, q[ks], st);
    }
#pragma unroll
    for (int j = 0; j < 4; j++) {
      f32x4 pw = (f32x4){st[4 * j], st[4 * j + 1], st[4 * j + 2], st[4 * j + 3]};
      *(f32x4*)(sxw + (j << 13)) = pw;
    }
    __syncthreads();  // B2: Kt reads done, partials visible

    if (it < 127) stageK(it + 1);

#pragma unroll
    for (int j = 0; j < 4; j++) {
      f32x4 pv = *(const f32x4*)(sxp + (j << 13));
      st[4 * j] += pv[0]; st[4 * j + 1] += pv[1];
      st[4 * j + 2] += pv[2]; st[4 * j + 3] += pv[3];
    }

    float p[16];
#pragma unroll
    for (int r = 0; r < 16; r++) p[r] = __builtin_amdgcn_exp2f(st[r]);
    lacc += ((p[0] + p[1]) + (p[2] + p[3])) + ((p[4] + p[5]) + (p[6] + p[7])) +
            (((p[8] + p[9]) + (p[10] + p[11])) +
             ((p[12] + p[13]) + (p[14] + p[15])));

    uint32_t d0 = cvtpk(p[0], p[1]),  d1 = cvtpk(p[2], p[3]);
    uint32_t d2 = cvtpk(p[4], p[5]),  d3 = cvtpk(p[6], p[7]);
    uint32_t d4 = cvtpk(p[8], p[9]),  d5 = cvtpk(p[10], p[11]);
    uint32_t d6 = cvtpk(p[12], p[13]), d7 = cvtpk(p[14], p[15]);
    plswap(d0, d2); plswap(d1, d3);
    plswap(d4, d6); plswap(d5, d7);
    U u1; u1.d[0] = d0; u1.d[1] = d1; u1.d[2] = d2; u1.d[3] = d3;
    U u2; u2.d[0] = d4; u2.d[1] = d5; u2.d[2] = d6; u2.d[3] = d7;

#pragma unroll
    for (int tt = 0; tt < 8; tt++) {
      const char* vrow = Vt + (((whalf << 3) + tt) << 11);
      short8 v1 = *(const short8*)(vrow + voff1);
      short8 v2 = *(const short8*)(vrow + voff2);
      o[tt] = mfma32(u1.s, v1, o[tt]);
      o[tt] = mfma32(u2.s, v2, o[tt]);
    }
  }

  lacc += __shfl_xor(lacc, 32, 64);
  if (whalf == 0) Ls[(wpair << 5) + l31] = lacc;
  __syncthreads();

  float linv[16];
#pragma unroll
  for (int r = 0; r < 16; r++) {
    int qq = (r & 3) + ((r >> 2) << 3) + (hi << 2);
    linv[r] = 1.f / Ls[(wpair << 5) + qq];
  }
#pragma unroll
  for (int tt = 0; tt < 8; tt++) {
    size_t col = (size_t)h * 512 + (((whalf << 3) + tt) << 5) + l31;
#pragma unroll
    for (int r = 0; r < 16; r++) {
      int qq = qbase + (r & 3) + ((r >> 2) << 3) + (hi << 2);
      AO[(size_t)qq * 4096 + col] = f2bf(o[tt][r] * linv[r]);
    }
  }
}

// ---------------- K3: out conv, split-K GEMM (M=128 x N=128, Kslice=10240) -------
// Grid 512 = 32 M x 2 kslice x 8 ocb (ocb = bid&7 XCD-pinned; kslice pairs
// 8 bids apart -> same XCD -> A rows L2-shared). R9's conflict-free body,
// 160 BK=64 steps each, f32 partial out. 64KB LDS -> 2 blocks/CU.
__global__ __launch_bounds__(256, 2)
void k_outconv(const unsigned short* __restrict__ AO,
               const unsigned short* __restrict__ WB,
               float* __restrict__ P) {
  __shared__ __align__(16) unsigned short As[2][8192];
  __shared__ __align__(16) unsigned short Bs[2][8192];
  const int tid = threadIdx.x;
  const int lane = tid & 63, w = tid >> 6;
  const int wr = w >> 1, wc = w & 1;
  const int l15 = lane & 15, lg = lane >> 4;
  const int ocb = (blockIdx.x & 7) * 128;
  const int kslice = (blockIdx.x >> 3) & 1;
  const int i0 = (blockIdx.x >> 4) * 128;
  const int ksbase = kslice * 160;

  f32x4 acc[4][4];
#pragma unroll
  for (int i = 0; i < 4; i++)
#pragma unroll
    for (int j = 0; j < 4; j++) acc[i][j] = (f32x4){0.f, 0.f, 0.f, 0.f};

  auto stage = [&](int kabs, int d) {
    const int t = kabs >> 6;
    const int f0 = (kabs & 63) << 6;
    const int k0 = kabs << 6;
#pragma unroll
    for (int i = 0; i < 4; i++) {  // A: 1024 slots
      int s = tid + (i << 8);
      int row = s >> 3, c = s & 7;
      int cs = c ^ (row & 7);
      int sr = refl4096(i0 + row + t - 2);
      gl_lds16(AO + (size_t)sr * 4096 + f0 + (cs << 3),
               (char*)As[d] + (size_t)s * 16);
    }
#pragma unroll
    for (int i = 0; i < 4; i++) {  // B: 1024 slots
      int s = tid + (i << 8);
      int row = s >> 3, c = s & 7;
      int cs = c ^ (row & 7);
      gl_lds16(WB + (size_t)(ocb + row) * 20480 + k0 + (cs << 3),
               (char*)Bs[d] + (size_t)s * 16);
    }
  };

  stage(ksbase, 0);

  for (int ks = 0; ks < 160; ks++) {
    const int d = ks & 1;
    __syncthreads();  // buf[d] staged loads landed; all waves done with buf[d^1]
    if (ks < 159) stage(ksbase + ks + 1, d ^ 1);
#pragma unroll
    for (int kk = 0; kk < 2; kk++) {
      short8 af[4], bq[4];
#pragma unroll
      for (int i = 0; i < 4; i++) {
        int row = (wr << 6) + (i << 4) + l15;
        af[i] = *(const short8*)((char*)As[d] + (row << 7) +
                                 ((((kk << 2) + lg) ^ (row & 7)) << 4));
      }
#pragma unroll
      for (int j = 0; j < 4; j++) {
        int row = (wc << 6) + (j << 4) + l15;
        bq[j] = *(const short8*)((char*)Bs[d] + (row << 7) +
                                 ((((kk << 2) + lg) ^ (row & 7)) << 4));
      }
#pragma unroll
      for (int i = 0; i < 4; i++)
#pragma unroll
        for (int j = 0; j < 4; j++) acc[i][j] = mfma16(af[i], bq[j], acc[i][j]);
    }
  }
#pragma unroll
  for (int i = 0; i < 4; i++)
#pragma unroll
    for (int j = 0; j < 4; j++) {
      int oc = ocb + (wc << 6) + (j << 4) + l15;
      int pos = i0 + (wr << 6) + (i << 4) + (lg << 2);
      *(f32x4*)(P + ((size_t)kslice * 1024 + oc) * 4096 + pos) = acc[i][j];
    }
}

// ---------------- launch ----------------
extern "C" void kernel_launch(void* const* d_in, const int* in_sizes, int n_in,
                              void* d_out, int out_size, void* d_ws,
                              size_t ws_size, hipStream_t stream) {
  const float* x = (const float*)d_in[0];
  const float* Wq = (const float*)d_in[1];
  const float* Wkv = (const float*)d_in[2];
  const float* Wout = (const float*)d_in[3];
  float* out = (float*)d_out;
  char* ws = (char*)d_ws;

  const size_t SEG = 33554432;  // 32 MiB
  unsigned short* Qg = (unsigned short*)ws;
  unsigned short* Kg = (unsigned short*)(ws + SEG);
  unsigned short* Vg = (unsigned short*)(ws + 2 * SEG);
  unsigned short* AO = (unsigned short*)(ws + 3 * SEG);
  unsigned short* xb = AO;  // overlays AO (dead until k_attn writes it)
  float* Pp = (float*)(ws + 2 * SEG);  // partials overlay Vg (dead in outconv)
  unsigned short* WB1 = (unsigned short*)(ws + 4 * SEG);  // ends at 136,183,808

  // WB2: dedicated region if ws allows (convert Wout once); else overlay Qg/Kg
  // and reconvert per batch.
  const size_t WB2_OFF = 136183808;               // WB1 end, 16B-aligned
  const size_t WB2_BYTES = (size_t)1024 * 20480 * 2;
  const bool wb2_once = ws_size >= WB2_OFF + WB2_BYTES;
  unsigned short* WB2 =
      wb2_once ? (unsigned short*)(ws + WB2_OFF) : (unsigned short*)ws;

  k_convw_qkv<<<3840, 256, 0, stream>>>(Wq, Wkv, WB1);
  if (wb2_once) k_convw_out<<<1024, 256, 0, stream>>>(Wout, WB2);
  for (int b = 0; b < 2; b++) {
    k_convx<<<2048, 256, 0, stream>>>(x, xb, b);
    k_qkv<<<dim3(32, 12, 8), 256, 0, stream>>>(xb, WB1, Qg, Kg, Vg);
    k_attn<<<256, 512, 0, stream>>>(Qg, Kg, Vg, AO);
    if (!wb2_once) k_convw_out<<<1024, 256, 0, stream>>>(Wout, WB2);
    k_outconv<<<512, 256, 0, stream>>>(AO, WB2, Pp);
    k_reduce<<<4096, 256, 0, stream>>>(Pp, out, b);
  }
}

// Round 15
// 1405.674 us; speedup vs baseline: 2.1587x; 1.0066x over previous
//
#include <hip/hip_runtime.h>
#include <stdint.h>

// Seq_CNN_Big_Attention: qkv 1x5 conv (reflect pad) -> flash attn (head dim 512)
// -> 8x5 out conv. bf16 MFMA pipeline, per-batch sequential to bound ws.
// R15: k_attn: stageV joined with stageK post-B2 (R7 placement; post-B1 V was
//      drained by B2's implicit vmcnt(0)). k_qkv: 1-barrier dbuf pipeline.
//      Rest identical to R14 (split-K outconv, XCD pinning, partials+reduce).

typedef __attribute__((ext_vector_type(8))) short short8;
typedef __attribute__((ext_vector_type(4))) short short4v;
typedef __attribute__((ext_vector_type(2))) short short2v;
typedef __attribute__((ext_vector_type(4))) float f32x4;
typedef __attribute__((ext_vector_type(16))) float f32x16;

__device__ __forceinline__ f32x4 mfma16(short8 a, short8 b, f32x4 c) {
  return __builtin_amdgcn_mfma_f32_16x16x32_bf16(a, b, c, 0, 0, 0);
}
__device__ __forceinline__ f32x16 mfma32(short8 a, short8 b, f32x16 c) {
  return __builtin_amdgcn_mfma_f32_32x32x16_bf16(a, b, c, 0, 0, 0);
}

__device__ __forceinline__ unsigned short f2bf(float f) {  // RNE f32->bf16
  union { float f; uint32_t u; } v; v.f = f;
  uint32_t r = (v.u + 0x7fffu + ((v.u >> 16) & 1u)) >> 16;
  return (unsigned short)r;
}

__device__ __forceinline__ uint32_t cvtpk(float lo, float hi) {
  uint32_t r;
  asm volatile("v_cvt_pk_bf16_f32 %0, %1, %2" : "=v"(r) : "v"(lo), "v"(hi));
  return r;
}
__device__ __forceinline__ void plswap(uint32_t& a, uint32_t& b) {
  asm volatile("v_permlane32_swap_b32 %0, %1" : "+v"(a), "+v"(b));
}

__device__ __forceinline__ int refl4096(int p) {  // reflect pad-2 index
  p = p < 0 ? -p : p;
  return p >= 4096 ? 8190 - p : p;
}

__device__ __forceinline__ void gl_lds16(const void* g, void* l) {
  __builtin_amdgcn_global_load_lds(
      (const __attribute__((address_space(1))) void*)g,
      (__attribute__((address_space(3))) void*)l, 16, 0, 0);
}

// ---------------- converters ----------------
__global__ void k_convw_qkv(const float* __restrict__ Wq,
                            const float* __restrict__ Wkv,
                            unsigned short* __restrict__ out) {
  int e = blockIdx.x * 256 + threadIdx.x;  // 1536*640 exact
  int oc = e / 640, k = e - oc * 640;
  int ci = k & 127, t = k >> 7;
  float w = (oc < 512) ? Wq[oc * 640 + ci * 5 + t]
                       : Wkv[(oc - 512) * 640 + ci * 5 + t];
  out[e] = f2bf(w);
}

// x (f32, one batch) -> xb bf16 [n][m][c] contiguous
__global__ __launch_bounds__(256)
void k_convx(const float* __restrict__ x, unsigned short* __restrict__ xb,
             int b) {
  int e = (blockIdx.x * 256 + threadIdx.x) * 8;  // 4194304 per batch
  const float* src = x + (size_t)b * 4194304 + e;
  f32x4 v0 = *(const f32x4*)src;
  f32x4 v1 = *(const f32x4*)(src + 4);
  short8 pk;
  pk[0] = (short)f2bf(v0[0]); pk[1] = (short)f2bf(v0[1]);
  pk[2] = (short)f2bf(v0[2]); pk[3] = (short)f2bf(v0[3]);
  pk[4] = (short)f2bf(v1[0]); pk[5] = (short)f2bf(v1[1]);
  pk[6] = (short)f2bf(v1[2]); pk[7] = (short)f2bf(v1[3]);
  *(short8*)(xb + e) = pk;
}

// one block per oc row: coalesced f32x4 read -> LDS bf16 -> coalesced write
__global__ __launch_bounds__(256)
void k_convw_out(const float* __restrict__ Wout,
                 unsigned short* __restrict__ out) {
  __shared__ unsigned short row_l[20480];
  const int oc = blockIdx.x;
  const int tid = threadIdx.x;
  const float* src = Wout + (size_t)oc * 20480;
#pragma unroll
  for (int i0 = 0; i0 < 5120; i0 += 256) {  // 20 rounds of f32x4
    int i = i0 + tid;
    f32x4 v = *(const f32x4*)(src + (size_t)i * 4);
    short4v pk;
    pk[0] = (short)f2bf(v[0]); pk[1] = (short)f2bf(v[1]);
    pk[2] = (short)f2bf(v[2]); pk[3] = (short)f2bf(v[3]);
    *(short4v*)(row_l + i * 4) = pk;
  }
  __syncthreads();
  unsigned short* drow = out + (size_t)oc * 20480;
#pragma unroll
  for (int r0 = 0; r0 < 20480; r0 += 512) {  // 40 rounds of ushort2
    int e = r0 + tid * 2;
    int t0 = e >> 12, ft0 = e & 4095;
    int t1 = (e + 1) >> 12, ft1 = (e + 1) & 4095;
    short2v pk;
    pk[0] = (short)row_l[(ft0 >> 3) * 40 + (ft0 & 7) * 5 + t0];
    pk[1] = (short)row_l[(ft1 >> 3) * 40 + (ft1 & 7) * 5 + t1];
    *(short2v*)(drow + e) = pk;
  }
}

// partial sum: out[b] = P[0] + P[1]
__global__ __launch_bounds__(256)
void k_reduce(const float* __restrict__ P, float* __restrict__ outp, int b) {
  int e = (blockIdx.x * 256 + threadIdx.x) * 4;  // 4194304 elements
  f32x4 a = *(const f32x4*)(P + e);
  f32x4 c = *(const f32x4*)(P + 4194304 + e);
  f32x4 s = (f32x4){a[0] + c[0], a[1] + c[1], a[2] + c[2], a[3] + c[3]};
  *(f32x4*)(outp + (size_t)b * 4194304 + e) = s;
}

// ---------------- K1: qkv conv as GEMM (M=128pos x N=128oc, K=640) ----------------
// R15: 1-barrier dbuf pipeline (proven in k_outconv): per step, __syncthreads
// drains the prefetch issued LAST step, then issue stage(ks+1)->buf[d^1] and
// compute buf[d].
__global__ __launch_bounds__(256, 2)
void k_qkv(const unsigned short* __restrict__ xb,
           const unsigned short* __restrict__ Wb,
           unsigned short* __restrict__ Qg, unsigned short* __restrict__ Kg,
           unsigned short* __restrict__ Vg) {
  __shared__ __align__(16) unsigned short As[2][8192];
  __shared__ __align__(16) unsigned short Bs[2][8192];
  const int tid = threadIdx.x;
  const int lane = tid & 63, w = tid >> 6;
  const int wr = w >> 1, wc = w & 1;
  const int l15 = lane & 15, lg = lane >> 4;
  const int p0 = blockIdx.x * 128;
  const int ocb = blockIdx.y * 128;
  const int m = blockIdx.z;

  f32x4 acc[4][4];
#pragma unroll
  for (int i = 0; i < 4; i++)
#pragma unroll
    for (int j = 0; j < 4; j++) acc[i][j] = (f32x4){0.f, 0.f, 0.f, 0.f};

  auto stage = [&](int ks, int d) {
    const int t = ks >> 1;
    const int ci0 = (ks & 1) << 6;
    // stage A: im2col 128 pos x 64 ci from xb, 8x16B chunks, chunk^=(row&7)
#pragma unroll
    for (int i = 0; i < 4; i++) {
      int s = tid + (i << 8);
      int row = s >> 3, c = s & 7;
      int cs = c ^ (row & 7);
      int xn = refl4096(p0 + row - 2 + t);
      gl_lds16(xb + (((size_t)xn << 3) + m) * 128 + ci0 + (cs << 3),
               (char*)As[d] + (size_t)s * 16);
    }
    // stage B: bf16 weights straight to LDS (inverse-swizzled source)
#pragma unroll
    for (int c = 0; c < 4; c++) {
      int sb = ((c << 2) + w) << 6;
      int slot = sb + lane;
      int row = slot >> 3, cc = slot & 7;
      int cs = cc ^ (row & 7);
      gl_lds16(Wb + (size_t)(ocb + row) * 640 + (ks << 6) + (cs << 3),
               (char*)Bs[d] + (size_t)sb * 16);
    }
  };

  stage(0, 0);

  for (int ks = 0; ks < 10; ks++) {
    const int d = ks & 1;
    __syncthreads();  // buf[d] staged loads landed; all waves done with buf[d^1]
    if (ks < 9) stage(ks + 1, d ^ 1);
#pragma unroll
    for (int kk = 0; kk < 2; kk++) {
      short8 af[4], bq[4];
#pragma unroll
      for (int i = 0; i < 4; i++) {
        int row = (wr << 6) + (i << 4) + l15;
        af[i] = *(const short8*)((char*)As[d] + (row << 7) +
                                 ((((kk << 2) + lg) ^ (row & 7)) << 4));
      }
#pragma unroll
      for (int j = 0; j < 4; j++) {
        int row = (wc << 6) + (j << 4) + l15;
        bq[j] = *(const short8*)((char*)Bs[d] + (row << 7) +
                                 ((((kk << 2) + lg) ^ (row & 7)) << 4));
      }
#pragma unroll
      for (int i = 0; i < 4; i++)
#pragma unroll
        for (int j = 0; j < 4; j++) acc[i][j] = mfma16(af[i], bq[j], acc[i][j]);
    }
  }

  const int region = ocb >> 9;  // 0:Q 1:K 2:V
  const float QSCALE = 0.18033688f;  // 1/8 * log2(e)
#pragma unroll
  for (int i = 0; i < 4; i++) {
    const int posb = p0 + (wr << 6) + (i << 4) + (lg << 2);
#pragma unroll
    for (int j = 0; j < 4; j++) {
      const int oc = ocb + (wc << 6) + (j << 4) + l15;
      const int ocr = oc & 511;
      const int hh = ocr >> 6, dd = ocr & 63;
      const int f = (dd << 3) + m;
      if (region == 0) {
        size_t base = (size_t)hh * 4096 * 512 + f;
#pragma unroll
        for (int r = 0; r < 4; r++)
          Qg[base + (size_t)(posb + r) * 512] = f2bf(acc[i][j][r] * QSCALE);
      } else if (region == 1) {
        size_t base = (size_t)hh * 4096 * 512 + f;
#pragma unroll
        for (int r = 0; r < 4; r++)
          Kg[base + (size_t)(posb + r) * 512] = f2bf(acc[i][j][r]);
      } else {
        short4v pk;
#pragma unroll
        for (int r = 0; r < 4; r++) pk[r] = (short)f2bf(acc[i][j][r]);
        *(short4v*)(Vg + ((size_t)hh * 512 + f) * 4096 + posb) = pk;
      }
    }
  }
}

// ---------------- K2: flash attention, 8 waves = 4 pairs x 32 q, f-split ----------
// R15: both stages post-B2 (R7 placement) -> they drain at the NEXT B1, fully
// covered by exchange+exp+pack+PV. B2 waits on nothing.
__global__ __launch_bounds__(512, 2)
void k_attn(const unsigned short* __restrict__ Qg,
            const unsigned short* __restrict__ Kg,
            const unsigned short* __restrict__ Vg,
            unsigned short* __restrict__ AO) {
  // Kt [0,32K) | Vt0 [32K,64K) | Vt1 [64K,96K) | Sx [96K,128K) | Ls 512B
  __shared__ __align__(16) char lds[131584];
  char* Kt = lds;
  char* Vt0 = lds + 32768;
  char* Vt1 = lds + 65536;
  char* Sx = lds + 98304;
  float* Ls = (float*)(lds + 131072);

  const int tid = threadIdx.x;
  const int lane = tid & 63, w = tid >> 6;
  const int l31 = lane & 31, hi = lane >> 5;
  const int wpair = w >> 1, whalf = w & 1;
  const int h = blockIdx.x & 7;          // XCD-pinned head
  const int qblk = blockIdx.x >> 3;
  const int qbase = qblk * 128 + wpair * 32;
  const int fh = whalf << 8;  // 0 or 256

  const size_t kb = (size_t)h * 4096 * 512;
  const size_t vb = (size_t)h * 512 * 4096;

  short8 q[16];
  {
    const unsigned short* qp =
        Qg + ((size_t)h * 4096 + qbase + l31) * 512 + fh + hi * 8;
#pragma unroll
    for (int ks = 0; ks < 16; ks++) q[ks] = *(const short8*)(qp + ks * 16);
  }

  f32x16 o[8];
#pragma unroll
  for (int t = 0; t < 8; t++)
#pragma unroll
    for (int e = 0; e < 16; e++) o[t][e] = 0.f;
  float lacc = 0.f;

  // PV read constants (R5-verified)
  const int rb = l31 >> 1;
  const int swz = rb & 7;
  const int cg0 = ((l31 & 1) << 2) + hi;
  const int voff1 = rb * 128 + ((cg0 ^ swz) << 4);
  const int voff2 = rb * 128 + (((cg0 + 2) ^ swz) << 4);

  // Sx: byte = j*8192 + w*1024 + lane*16 (conflict-free b128)
  char* sxw = Sx + (w << 10) + (lane << 4);
  char* sxp = Sx + ((w ^ 1) << 10) + (lane << 4);

  union U { uint32_t d[4]; short8 s; };

  auto stageK = [&](int it) {
    const int key0 = it << 5;
#pragma unroll
    for (int i = 0; i < 4; i++) {
      int s = tid + (i << 9);
      int r = s >> 6, c = s & 63;
      gl_lds16(Kg + kb + (size_t)(key0 + r) * 512 + ((c ^ r) << 3),
               Kt + (size_t)s * 16);
    }
  };
  auto stageV = [&](int it, char* Vt) {
    const int key0 = it << 5;
#pragma unroll
    for (int i = 0; i < 4; i++) {
      int s = tid + (i << 9);
      int rp = s >> 3, c = s & 7;
      int cu = c ^ (rp & 7);
      int f = (rp << 1) + (cu >> 2);
      gl_lds16(Vg + vb + (size_t)f * 4096 + key0 + ((cu & 3) << 3),
               Vt + (size_t)s * 16);
    }
  };

  stageK(0);
  stageV(0, Vt0);

  for (int it = 0; it < 128; it++) {
    char* Vt = (it & 1) ? Vt1 : Vt0;
    char* Vn = (it & 1) ? Vt0 : Vt1;
    __syncthreads();  // B1: staged tiles landed

    f32x16 st;
#pragma unroll
    for (int e = 0; e < 16; e++) st[e] = 0.f;
#pragma unroll
    for (int ks = 0; ks < 16; ks++) {
      int ch = ((fh >> 3) + (ks << 1) + hi) ^ l31;
      short8 kfrag = *(const short8*)(Kt + (l31 << 10) + (ch << 4));
      st = mfma32(kfrag, q[ks], st);
    }
#pragma unroll
    for (int j = 0; j < 4; j++) {
      f32x4 pw = (f32x4){st[4 * j], st[4 * j + 1], st[4 * j + 2], st[4 * j + 3]};
      *(f32x4*)(sxw + (j << 13)) = pw;
    }
    __syncthreads();  // B2: Kt reads done, partials visible (waits on nothing else)

    if (it < 127) {  // both stages fly under exchange+exp+pack+PV, drain at B1
      stageK(it + 1);
      stageV(it + 1, Vn);
    }

#pragma unroll
    for (int j = 0; j < 4; j++) {
      f32x4 pv = *(const f32x4*)(sxp + (j << 13));
      st[4 * j] += pv[0]; st[4 * j + 1] += pv[1];
      st[4 * j + 2] += pv[2]; st[4 * j + 3] += pv[3];
    }

    float p[16];
#pragma unroll
    for (int r = 0; r < 16; r++) p[r] = __builtin_amdgcn_exp2f(st[r]);
    lacc += ((p[0] + p[1]) + (p[2] + p[3])) + ((p[4] + p[5]) + (p[6] + p[7])) +
            (((p[8] + p[9]) + (p[10] + p[11])) +
             ((p[12] + p[13]) + (p[14] + p[15])));

    uint32_t d0 = cvtpk(p[0], p[1]),  d1 = cvtpk(p[2], p[3]);
    uint32_t d2 = cvtpk(p[4], p[5]),  d3 = cvtpk(p[6], p[7]);
    uint32_t d4 = cvtpk(p[8], p[9]),  d5 = cvtpk(p[10], p[11]);
    uint32_t d6 = cvtpk(p[12], p[13]), d7 = cvtpk(p[14], p[15]);
    plswap(d0, d2); plswap(d1, d3);
    plswap(d4, d6); plswap(d5, d7);
    U u1; u1.d[0] = d0; u1.d[1] = d1; u1.d[2] = d2; u1.d[3] = d3;
    U u2; u2.d[0] = d4; u2.d[1] = d5; u2.d[2] = d6; u2.d[3] = d7;

#pragma unroll
    for (int tt = 0; tt < 8; tt++) {
      const char* vrow = Vt + (((whalf << 3) + tt) << 11);
      short8 v1 = *(const short8*)(vrow + voff1);
      short8 v2 = *(const short8*)(vrow + voff2);
      o[tt] = mfma32(u1.s, v1, o[tt]);
      o[tt] = mfma32(u2.s, v2, o[tt]);
    }
  }

  lacc += __shfl_xor(lacc, 32, 64);
  if (whalf == 0) Ls[(wpair << 5) + l31] = lacc;
  __syncthreads();

  float linv[16];
#pragma unroll
  for (int r = 0; r < 16; r++) {
    int qq = (r & 3) + ((r >> 2) << 3) + (hi << 2);
    linv[r] = 1.f / Ls[(wpair << 5) + qq];
  }
#pragma unroll
  for (int tt = 0; tt < 8; tt++) {
    size_t col = (size_t)h * 512 + (((whalf << 3) + tt) << 5) + l31;
#pragma unroll
    for (int r = 0; r < 16; r++) {
      int qq = qbase + (r & 3) + ((r >> 2) << 3) + (hi << 2);
      AO[(size_t)qq * 4096 + col] = f2bf(o[tt][r] * linv[r]);
    }
  }
}

// ---------------- K3: out conv, split-K GEMM (M=128 x N=128, Kslice=10240) -------
__global__ __launch_bounds__(256, 2)
void k_outconv(const unsigned short* __restrict__ AO,
               const unsigned short* __restrict__ WB,
               float* __restrict__ P) {
  __shared__ __align__(16) unsigned short As[2][8192];
  __shared__ __align__(16) unsigned short Bs[2][8192];
  const int tid = threadIdx.x;
  const int lane = tid & 63, w = tid >> 6;
  const int wr = w >> 1, wc = w & 1;
  const int l15 = lane & 15, lg = lane >> 4;
  const int ocb = (blockIdx.x & 7) * 128;
  const int kslice = (blockIdx.x >> 3) & 1;
  const int i0 = (blockIdx.x >> 4) * 128;
  const int ksbase = kslice * 160;

  f32x4 acc[4][4];
#pragma unroll
  for (int i = 0; i < 4; i++)
#pragma unroll
    for (int j = 0; j < 4; j++) acc[i][j] = (f32x4){0.f, 0.f, 0.f, 0.f};

  auto stage = [&](int kabs, int d) {
    const int t = kabs >> 6;
    const int f0 = (kabs & 63) << 6;
    const int k0 = kabs << 6;
#pragma unroll
    for (int i = 0; i < 4; i++) {  // A: 1024 slots
      int s = tid + (i << 8);
      int row = s >> 3, c = s & 7;
      int cs = c ^ (row & 7);
      int sr = refl4096(i0 + row + t - 2);
      gl_lds16(AO + (size_t)sr * 4096 + f0 + (cs << 3),
               (char*)As[d] + (size_t)s * 16);
    }
#pragma unroll
    for (int i = 0; i < 4; i++) {  // B: 1024 slots
      int s = tid + (i << 8);
      int row = s >> 3, c = s & 7;
      int cs = c ^ (row & 7);
      gl_lds16(WB + (size_t)(ocb + row) * 20480 + k0 + (cs << 3),
               (char*)Bs[d] + (size_t)s * 16);
    }
  };

  stage(ksbase, 0);

  for (int ks = 0; ks < 160; ks++) {
    const int d = ks & 1;
    __syncthreads();  // buf[d] staged loads landed; all waves done with buf[d^1]
    if (ks < 159) stage(ksbase + ks + 1, d ^ 1);
#pragma unroll
    for (int kk = 0; kk < 2; kk++) {
      short8 af[4], bq[4];
#pragma unroll
      for (int i = 0; i < 4; i++) {
        int row = (wr << 6) + (i << 4) + l15;
        af[i] = *(const short8*)((char*)As[d] + (row << 7) +
                                 ((((kk << 2) + lg) ^ (row & 7)) << 4));
      }
#pragma unroll
      for (int j = 0; j < 4; j++) {
        int row = (wc << 6) + (j << 4) + l15;
        bq[j] = *(const short8*)((char*)Bs[d] + (row << 7) +
                                 ((((kk << 2) + lg) ^ (row & 7)) << 4));
      }
#pragma unroll
      for (int i = 0; i < 4; i++)
#pragma unroll
        for (int j = 0; j < 4; j++) acc[i][j] = mfma16(af[i], bq[j], acc[i][j]);
    }
  }
#pragma unroll
  for (int i = 0; i < 4; i++)
#pragma unroll
    for (int j = 0; j < 4; j++) {
      int oc = ocb + (wc << 6) + (j << 4) + l15;
      int pos = i0 + (wr << 6) + (i << 4) + (lg << 2);
      *(f32x4*)(P + ((size_t)kslice * 1024 + oc) * 4096 + pos) = acc[i][j];
    }
}

// ---------------- launch ----------------
extern "C" void kernel_launch(void* const* d_in, const int* in_sizes, int n_in,
                              void* d_out, int out_size, void* d_ws,
                              size_t ws_size, hipStream_t stream) {
  const float* x = (const float*)d_in[0];
  const float* Wq = (const float*)d_in[1];
  const float* Wkv = (const float*)d_in[2];
  const float* Wout = (const float*)d_in[3];
  float* out = (float*)d_out;
  char* ws = (char*)d_ws;

  const size_t SEG = 33554432;  // 32 MiB
  unsigned short* Qg = (unsigned short*)ws;
  unsigned short* Kg = (unsigned short*)(ws + SEG);
  unsigned short* Vg = (unsigned short*)(ws + 2 * SEG);
  unsigned short* AO = (unsigned short*)(ws + 3 * SEG);
  unsigned short* xb = AO;  // overlays AO (dead until k_attn writes it)
  float* Pp = (float*)(ws + 2 * SEG);  // partials overlay Vg (dead in outconv)
  unsigned short* WB1 = (unsigned short*)(ws + 4 * SEG);  // ends at 136,183,808

  // WB2: dedicated region if ws allows (convert Wout once); else overlay Qg/Kg
  // and reconvert per batch.
  const size_t WB2_OFF = 136183808;               // WB1 end, 16B-aligned
  const size_t WB2_BYTES = (size_t)1024 * 20480 * 2;
  const bool wb2_once = ws_size >= WB2_OFF + WB2_BYTES;
  unsigned short* WB2 =
      wb2_once ? (unsigned short*)(ws + WB2_OFF) : (unsigned short*)ws;

  k_convw_qkv<<<3840, 256, 0, stream>>>(Wq, Wkv, WB1);
  if (wb2_once) k_convw_out<<<1024, 256, 0, stream>>>(Wout, WB2);
  for (int b = 0; b < 2; b++) {
    k_convx<<<2048, 256, 0, stream>>>(x, xb, b);
    k_qkv<<<dim3(32, 12, 8), 256, 0, stream>>>(xb, WB1, Qg, Kg, Vg);
    k_attn<<<256, 512, 0, stream>>>(Qg, Kg, Vg, AO);
    if (!wb2_once) k_convw_out<<<1024, 256, 0, stream>>>(Wout, WB2);
    k_outconv<<<512, 256, 0, stream>>>(AO, WB2, Pp);
    k_reduce<<<4096, 256, 0, stream>>>(Pp, out, b);
  }
}

// Round 16
// 1323.809 us; speedup vs baseline: 2.2922x; 1.0618x over previous
//
#include <hip/hip_runtime.h>
#include <stdint.h>

// Seq_CNN_Big_Attention: qkv 1x5 conv (reflect pad) -> flash attn (head dim 512)
// -> 8x5 out conv. bf16 MFMA pipeline, per-batch sequential to bound ws.
// R16: k_attn: stageV back post-B1 (R14 cfg; R15's post-B2 unbalanced the LDS
//      pipe, -4%), + T5 setprio around QK^T/PV MFMA clusters. k_outconv:
//      incremental staging addresses (VALU cut) + setprio. k_qkv keeps dbuf.

typedef __attribute__((ext_vector_type(8))) short short8;
typedef __attribute__((ext_vector_type(4))) short short4v;
typedef __attribute__((ext_vector_type(2))) short short2v;
typedef __attribute__((ext_vector_type(4))) float f32x4;
typedef __attribute__((ext_vector_type(16))) float f32x16;

__device__ __forceinline__ f32x4 mfma16(short8 a, short8 b, f32x4 c) {
  return __builtin_amdgcn_mfma_f32_16x16x32_bf16(a, b, c, 0, 0, 0);
}
__device__ __forceinline__ f32x16 mfma32(short8 a, short8 b, f32x16 c) {
  return __builtin_amdgcn_mfma_f32_32x32x16_bf16(a, b, c, 0, 0, 0);
}

__device__ __forceinline__ unsigned short f2bf(float f) {  // RNE f32->bf16
  union { float f; uint32_t u; } v; v.f = f;
  uint32_t r = (v.u + 0x7fffu + ((v.u >> 16) & 1u)) >> 16;
  return (unsigned short)r;
}

__device__ __forceinline__ uint32_t cvtpk(float lo, float hi) {
  uint32_t r;
  asm volatile("v_cvt_pk_bf16_f32 %0, %1, %2" : "=v"(r) : "v"(lo), "v"(hi));
  return r;
}
__device__ __forceinline__ void plswap(uint32_t& a, uint32_t& b) {
  asm volatile("v_permlane32_swap_b32 %0, %1" : "+v"(a), "+v"(b));
}

__device__ __forceinline__ int refl4096(int p) {  // reflect pad-2 index
  p = p < 0 ? -p : p;
  return p >= 4096 ? 8190 - p : p;
}

__device__ __forceinline__ void gl_lds16(const void* g, void* l) {
  __builtin_amdgcn_global_load_lds(
      (const __attribute__((address_space(1))) void*)g,
      (__attribute__((address_space(3))) void*)l, 16, 0, 0);
}

// ---------------- converters ----------------
__global__ void k_convw_qkv(const float* __restrict__ Wq,
                            const float* __restrict__ Wkv,
                            unsigned short* __restrict__ out) {
  int e = blockIdx.x * 256 + threadIdx.x;  // 1536*640 exact
  int oc = e / 640, k = e - oc * 640;
  int ci = k & 127, t = k >> 7;
  float w = (oc < 512) ? Wq[oc * 640 + ci * 5 + t]
                       : Wkv[(oc - 512) * 640 + ci * 5 + t];
  out[e] = f2bf(w);
}

// x (f32, one batch) -> xb bf16 [n][m][c] contiguous
__global__ __launch_bounds__(256)
void k_convx(const float* __restrict__ x, unsigned short* __restrict__ xb,
             int b) {
  int e = (blockIdx.x * 256 + threadIdx.x) * 8;  // 4194304 per batch
  const float* src = x + (size_t)b * 4194304 + e;
  f32x4 v0 = *(const f32x4*)src;
  f32x4 v1 = *(const f32x4*)(src + 4);
  short8 pk;
  pk[0] = (short)f2bf(v0[0]); pk[1] = (short)f2bf(v0[1]);
  pk[2] = (short)f2bf(v0[2]); pk[3] = (short)f2bf(v0[3]);
  pk[4] = (short)f2bf(v1[0]); pk[5] = (short)f2bf(v1[1]);
  pk[6] = (short)f2bf(v1[2]); pk[7] = (short)f2bf(v1[3]);
  *(short8*)(xb + e) = pk;
}

// one block per oc row: coalesced f32x4 read -> LDS bf16 -> coalesced write
__global__ __launch_bounds__(256)
void k_convw_out(const float* __restrict__ Wout,
                 unsigned short* __restrict__ out) {
  __shared__ unsigned short row_l[20480];
  const int oc = blockIdx.x;
  const int tid = threadIdx.x;
  const float* src = Wout + (size_t)oc * 20480;
#pragma unroll
  for (int i0 = 0; i0 < 5120; i0 += 256) {  // 20 rounds of f32x4
    int i = i0 + tid;
    f32x4 v = *(const f32x4*)(src + (size_t)i * 4);
    short4v pk;
    pk[0] = (short)f2bf(v[0]); pk[1] = (short)f2bf(v[1]);
    pk[2] = (short)f2bf(v[2]); pk[3] = (short)f2bf(v[3]);
    *(short4v*)(row_l + i * 4) = pk;
  }
  __syncthreads();
  unsigned short* drow = out + (size_t)oc * 20480;
#pragma unroll
  for (int r0 = 0; r0 < 20480; r0 += 512) {  // 40 rounds of ushort2
    int e = r0 + tid * 2;
    int t0 = e >> 12, ft0 = e & 4095;
    int t1 = (e + 1) >> 12, ft1 = (e + 1) & 4095;
    short2v pk;
    pk[0] = (short)row_l[(ft0 >> 3) * 40 + (ft0 & 7) * 5 + t0];
    pk[1] = (short)row_l[(ft1 >> 3) * 40 + (ft1 & 7) * 5 + t1];
    *(short2v*)(drow + e) = pk;
  }
}

// partial sum: out[b] = P[0] + P[1]
__global__ __launch_bounds__(256)
void k_reduce(const float* __restrict__ P, float* __restrict__ outp, int b) {
  int e = (blockIdx.x * 256 + threadIdx.x) * 4;  // 4194304 elements
  f32x4 a = *(const f32x4*)(P + e);
  f32x4 c = *(const f32x4*)(P + 4194304 + e);
  f32x4 s = (f32x4){a[0] + c[0], a[1] + c[1], a[2] + c[2], a[3] + c[3]};
  *(f32x4*)(outp + (size_t)b * 4194304 + e) = s;
}

// ---------------- K1: qkv conv as GEMM (M=128pos x N=128oc, K=640) ----------------
__global__ __launch_bounds__(256, 2)
void k_qkv(const unsigned short* __restrict__ xb,
           const unsigned short* __restrict__ Wb,
           unsigned short* __restrict__ Qg, unsigned short* __restrict__ Kg,
           unsigned short* __restrict__ Vg) {
  __shared__ __align__(16) unsigned short As[2][8192];
  __shared__ __align__(16) unsigned short Bs[2][8192];
  const int tid = threadIdx.x;
  const int lane = tid & 63, w = tid >> 6;
  const int wr = w >> 1, wc = w & 1;
  const int l15 = lane & 15, lg = lane >> 4;
  const int p0 = blockIdx.x * 128;
  const int ocb = blockIdx.y * 128;
  const int m = blockIdx.z;

  f32x4 acc[4][4];
#pragma unroll
  for (int i = 0; i < 4; i++)
#pragma unroll
    for (int j = 0; j < 4; j++) acc[i][j] = (f32x4){0.f, 0.f, 0.f, 0.f};

  auto stage = [&](int ks, int d) {
    const int t = ks >> 1;
    const int ci0 = (ks & 1) << 6;
#pragma unroll
    for (int i = 0; i < 4; i++) {
      int s = tid + (i << 8);
      int row = s >> 3, c = s & 7;
      int cs = c ^ (row & 7);
      int xn = refl4096(p0 + row - 2 + t);
      gl_lds16(xb + (((size_t)xn << 3) + m) * 128 + ci0 + (cs << 3),
               (char*)As[d] + (size_t)s * 16);
    }
#pragma unroll
    for (int c = 0; c < 4; c++) {
      int sb = ((c << 2) + w) << 6;
      int slot = sb + lane;
      int row = slot >> 3, cc = slot & 7;
      int cs = cc ^ (row & 7);
      gl_lds16(Wb + (size_t)(ocb + row) * 640 + (ks << 6) + (cs << 3),
               (char*)Bs[d] + (size_t)sb * 16);
    }
  };

  stage(0, 0);

  for (int ks = 0; ks < 10; ks++) {
    const int d = ks & 1;
    __syncthreads();  // buf[d] staged loads landed; all waves done with buf[d^1]
    if (ks < 9) stage(ks + 1, d ^ 1);
#pragma unroll
    for (int kk = 0; kk < 2; kk++) {
      short8 af[4], bq[4];
#pragma unroll
      for (int i = 0; i < 4; i++) {
        int row = (wr << 6) + (i << 4) + l15;
        af[i] = *(const short8*)((char*)As[d] + (row << 7) +
                                 ((((kk << 2) + lg) ^ (row & 7)) << 4));
      }
#pragma unroll
      for (int j = 0; j < 4; j++) {
        int row = (wc << 6) + (j << 4) + l15;
        bq[j] = *(const short8*)((char*)Bs[d] + (row << 7) +
                                 ((((kk << 2) + lg) ^ (row & 7)) << 4));
      }
#pragma unroll
      for (int i = 0; i < 4; i++)
#pragma unroll
        for (int j = 0; j < 4; j++) acc[i][j] = mfma16(af[i], bq[j], acc[i][j]);
    }
  }

  const int region = ocb >> 9;  // 0:Q 1:K 2:V
  const float QSCALE = 0.18033688f;  // 1/8 * log2(e)
#pragma unroll
  for (int i = 0; i < 4; i++) {
    const int posb = p0 + (wr << 6) + (i << 4) + (lg << 2);
#pragma unroll
    for (int j = 0; j < 4; j++) {
      const int oc = ocb + (wc << 6) + (j << 4) + l15;
      const int ocr = oc & 511;
      const int hh = ocr >> 6, dd = ocr & 63;
      const int f = (dd << 3) + m;
      if (region == 0) {
        size_t base = (size_t)hh * 4096 * 512 + f;
#pragma unroll
        for (int r = 0; r < 4; r++)
          Qg[base + (size_t)(posb + r) * 512] = f2bf(acc[i][j][r] * QSCALE);
      } else if (region == 1) {
        size_t base = (size_t)hh * 4096 * 512 + f;
#pragma unroll
        for (int r = 0; r < 4; r++)
          Kg[base + (size_t)(posb + r) * 512] = f2bf(acc[i][j][r]);
      } else {
        short4v pk;
#pragma unroll
        for (int r = 0; r < 4; r++) pk[r] = (short)f2bf(acc[i][j][r]);
        *(short4v*)(Vg + ((size_t)hh * 512 + f) * 4096 + posb) = pk;
      }
    }
  }
}

// ---------------- K2: flash attention, 8 waves = 4 pairs x 32 q, f-split ----------
// R16 = R14 placement (V post-B1, K post-B2) + T5 setprio around MFMA clusters.
__global__ __launch_bounds__(512, 2)
void k_attn(const unsigned short* __restrict__ Qg,
            const unsigned short* __restrict__ Kg,
            const unsigned short* __restrict__ Vg,
            unsigned short* __restrict__ AO) {
  // Kt [0,32K) | Vt0 [32K,64K) | Vt1 [64K,96K) | Sx [96K,128K) | Ls 512B
  __shared__ __align__(16) char lds[131584];
  char* Kt = lds;
  char* Vt0 = lds + 32768;
  char* Vt1 = lds + 65536;
  char* Sx = lds + 98304;
  float* Ls = (float*)(lds + 131072);

  const int tid = threadIdx.x;
  const int lane = tid & 63, w = tid >> 6;
  const int l31 = lane & 31, hi = lane >> 5;
  const int wpair = w >> 1, whalf = w & 1;
  const int h = blockIdx.x & 7;          // XCD-pinned head
  const int qblk = blockIdx.x >> 3;
  const int qbase = qblk * 128 + wpair * 32;
  const int fh = whalf << 8;  // 0 or 256

  const size_t kb = (size_t)h * 4096 * 512;
  const size_t vb = (size_t)h * 512 * 4096;

  short8 q[16];
  {
    const unsigned short* qp =
        Qg + ((size_t)h * 4096 + qbase + l31) * 512 + fh + hi * 8;
#pragma unroll
    for (int ks = 0; ks < 16; ks++) q[ks] = *(const short8*)(qp + ks * 16);
  }

  f32x16 o[8];
#pragma unroll
  for (int t = 0; t < 8; t++)
#pragma unroll
    for (int e = 0; e < 16; e++) o[t][e] = 0.f;
  float lacc = 0.f;

  // PV read constants (R5-verified)
  const int rb = l31 >> 1;
  const int swz = rb & 7;
  const int cg0 = ((l31 & 1) << 2) + hi;
  const int voff1 = rb * 128 + ((cg0 ^ swz) << 4);
  const int voff2 = rb * 128 + (((cg0 + 2) ^ swz) << 4);

  // Sx: byte = j*8192 + w*1024 + lane*16 (conflict-free b128)
  char* sxw = Sx + (w << 10) + (lane << 4);
  char* sxp = Sx + ((w ^ 1) << 10) + (lane << 4);

  union U { uint32_t d[4]; short8 s; };

  auto stageK = [&](int it) {
    const int key0 = it << 5;
#pragma unroll
    for (int i = 0; i < 4; i++) {
      int s = tid + (i << 9);
      int r = s >> 6, c = s & 63;
      gl_lds16(Kg + kb + (size_t)(key0 + r) * 512 + ((c ^ r) << 3),
               Kt + (size_t)s * 16);
    }
  };
  auto stageV = [&](int it, char* Vt) {
    const int key0 = it << 5;
#pragma unroll
    for (int i = 0; i < 4; i++) {
      int s = tid + (i << 9);
      int rp = s >> 3, c = s & 7;
      int cu = c ^ (rp & 7);
      int f = (rp << 1) + (cu >> 2);
      gl_lds16(Vg + vb + (size_t)f * 4096 + key0 + ((cu & 3) << 3),
               Vt + (size_t)s * 16);
    }
  };

  stageK(0);
  stageV(0, Vt0);

  for (int it = 0; it < 128; it++) {
    char* Vt = (it & 1) ? Vt1 : Vt0;
    char* Vn = (it & 1) ? Vt0 : Vt1;
    __syncthreads();  // B1: staged tiles landed

    // V(t+1) post-B1: its LDS writes overlap the read-light QK^T phase
    // (R14 cfg; R15's post-B2 placement congested the tail, -4%).
    if (it < 127) stageV(it + 1, Vn);

    f32x16 st;
#pragma unroll
    for (int e = 0; e < 16; e++) st[e] = 0.f;
    __builtin_amdgcn_s_setprio(1);
#pragma unroll
    for (int ks = 0; ks < 16; ks++) {
      int ch = ((fh >> 3) + (ks << 1) + hi) ^ l31;
      short8 kfrag = *(const short8*)(Kt + (l31 << 10) + (ch << 4));
      st = mfma32(kfrag, q[ks], st);
    }
    __builtin_amdgcn_s_setprio(0);
#pragma unroll
    for (int j = 0; j < 4; j++) {
      f32x4 pw = (f32x4){st[4 * j], st[4 * j + 1], st[4 * j + 2], st[4 * j + 3]};
      *(f32x4*)(sxw + (j << 13)) = pw;
    }
    __syncthreads();  // B2: Kt reads done, partials visible

    if (it < 127) stageK(it + 1);

#pragma unroll
    for (int j = 0; j < 4; j++) {
      f32x4 pv = *(const f32x4*)(sxp + (j << 13));
      st[4 * j] += pv[0]; st[4 * j + 1] += pv[1];
      st[4 * j + 2] += pv[2]; st[4 * j + 3] += pv[3];
    }

    float p[16];
#pragma unroll
    for (int r = 0; r < 16; r++) p[r] = __builtin_amdgcn_exp2f(st[r]);
    lacc += ((p[0] + p[1]) + (p[2] + p[3])) + ((p[4] + p[5]) + (p[6] + p[7])) +
            (((p[8] + p[9]) + (p[10] + p[11])) +
             ((p[12] + p[13]) + (p[14] + p[15])));

    uint32_t d0 = cvtpk(p[0], p[1]),  d1 = cvtpk(p[2], p[3]);
    uint32_t d2 = cvtpk(p[4], p[5]),  d3 = cvtpk(p[6], p[7]);
    uint32_t d4 = cvtpk(p[8], p[9]),  d5 = cvtpk(p[10], p[11]);
    uint32_t d6 = cvtpk(p[12], p[13]), d7 = cvtpk(p[14], p[15]);
    plswap(d0, d2); plswap(d1, d3);
    plswap(d4, d6); plswap(d5, d7);
    U u1; u1.d[0] = d0; u1.d[1] = d1; u1.d[2] = d2; u1.d[3] = d3;
    U u2; u2.d[0] = d4; u2.d[1] = d5; u2.d[2] = d6; u2.d[3] = d7;

    __builtin_amdgcn_s_setprio(1);
#pragma unroll
    for (int tt = 0; tt < 8; tt++) {
      const char* vrow = Vt + (((whalf << 3) + tt) << 11);
      short8 v1 = *(const short8*)(vrow + voff1);
      short8 v2 = *(const short8*)(vrow + voff2);
      o[tt] = mfma32(u1.s, v1, o[tt]);
      o[tt] = mfma32(u2.s, v2, o[tt]);
    }
    __builtin_amdgcn_s_setprio(0);
  }

  lacc += __shfl_xor(lacc, 32, 64);
  if (whalf == 0) Ls[(wpair << 5) + l31] = lacc;
  __syncthreads();

  float linv[16];
#pragma unroll
  for (int r = 0; r < 16; r++) {
    int qq = (r & 3) + ((r >> 2) << 3) + (hi << 2);
    linv[r] = 1.f / Ls[(wpair << 5) + qq];
  }
#pragma unroll
  for (int tt = 0; tt < 8; tt++) {
    size_t col = (size_t)h * 512 + (((whalf << 3) + tt) << 5) + l31;
#pragma unroll
    for (int r = 0; r < 16; r++) {
      int qq = qbase + (r & 3) + ((r >> 2) << 3) + (hi << 2);
      AO[(size_t)qq * 4096 + col] = f2bf(o[tt][r] * linv[r]);
    }
  }
}

// ---------------- K3: out conv, split-K GEMM (M=128 x N=128, Kslice=10240) -------
// R16: incremental staging addresses (A recomputed only at t-boundaries, else
// +=64; B bases hoisted) + setprio around MFMA cluster.
__global__ __launch_bounds__(256, 2)
void k_outconv(const unsigned short* __restrict__ AO,
               const unsigned short* __restrict__ WB,
               float* __restrict__ P) {
  __shared__ __align__(16) unsigned short As[2][8192];
  __shared__ __align__(16) unsigned short Bs[2][8192];
  const int tid = threadIdx.x;
  const int lane = tid & 63, w = tid >> 6;
  const int wr = w >> 1, wc = w & 1;
  const int l15 = lane & 15, lg = lane >> 4;
  const int ocb = (blockIdx.x & 7) * 128;
  const int kslice = (blockIdx.x >> 3) & 1;
  const int i0 = (blockIdx.x >> 4) * 128;
  const int ksbase = kslice * 160;

  f32x4 acc[4][4];
#pragma unroll
  for (int i = 0; i < 4; i++)
#pragma unroll
    for (int j = 0; j < 4; j++) acc[i][j] = (f32x4){0.f, 0.f, 0.f, 0.f};

  // B source bases (row, swizzle invariant across steps)
  size_t bbase[4];
#pragma unroll
  for (int i = 0; i < 4; i++) {
    int s = tid + (i << 8);
    int row = s >> 3, c = s & 7;
    int cs = c ^ (row & 7);
    bbase[i] = (size_t)(ocb + row) * 20480 + (cs << 3);
  }

  size_t aoff[4];
  uint32_t bk = 0;
  bool first = true;

  auto stage = [&](int kabs, int d) {
    if (first) {
      bk = (uint32_t)kabs << 6;
    } else {
      bk += 64;
    }
    if (first || (kabs & 63) == 0) {
      const int t = kabs >> 6;
      const int f0 = (kabs & 63) << 6;
#pragma unroll
      for (int i = 0; i < 4; i++) {
        int s = tid + (i << 8);
        int row = s >> 3, c = s & 7;
        int cs = c ^ (row & 7);
        int sr = refl4096(i0 + row + t - 2);
        aoff[i] = (size_t)sr * 4096 + f0 + (cs << 3);
      }
      first = false;
    } else {
#pragma unroll
      for (int i = 0; i < 4; i++) aoff[i] += 64;
    }
#pragma unroll
    for (int i = 0; i < 4; i++) {
      int s = tid + (i << 8);
      gl_lds16(AO + aoff[i], (char*)As[d] + (size_t)s * 16);
    }
#pragma unroll
    for (int i = 0; i < 4; i++) {
      int s = tid + (i << 8);
      gl_lds16(WB + bbase[i] + bk, (char*)Bs[d] + (size_t)s * 16);
    }
  };

  stage(ksbase, 0);

  for (int ks = 0; ks < 160; ks++) {
    const int d = ks & 1;
    __syncthreads();  // buf[d] staged loads landed; all waves done with buf[d^1]
    if (ks < 159) stage(ksbase + ks + 1, d ^ 1);
    __builtin_amdgcn_s_setprio(1);
#pragma unroll
    for (int kk = 0; kk < 2; kk++) {
      short8 af[4], bq[4];
#pragma unroll
      for (int i = 0; i < 4; i++) {
        int row = (wr << 6) + (i << 4) + l15;
        af[i] = *(const short8*)((char*)As[d] + (row << 7) +
                                 ((((kk << 2) + lg) ^ (row & 7)) << 4));
      }
#pragma unroll
      for (int j = 0; j < 4; j++) {
        int row = (wc << 6) + (j << 4) + l15;
        bq[j] = *(const short8*)((char*)Bs[d] + (row << 7) +
                                 ((((kk << 2) + lg) ^ (row & 7)) << 4));
      }
#pragma unroll
      for (int i = 0; i < 4; i++)
#pragma unroll
        for (int j = 0; j < 4; j++) acc[i][j] = mfma16(af[i], bq[j], acc[i][j]);
    }
    __builtin_amdgcn_s_setprio(0);
  }
#pragma unroll
  for (int i = 0; i < 4; i++)
#pragma unroll
    for (int j = 0; j < 4; j++) {
      int oc = ocb + (wc << 6) + (j << 4) + l15;
      int pos = i0 + (wr << 6) + (i << 4) + (lg << 2);
      *(f32x4*)(P + ((size_t)kslice * 1024 + oc) * 4096 + pos) = acc[i][j];
    }
}

// ---------------- launch ----------------
extern "C" void kernel_launch(void* const* d_in, const int* in_sizes, int n_in,
                              void* d_out, int out_size, void* d_ws,
                              size_t ws_size, hipStream_t stream) {
  const float* x = (const float*)d_in[0];
  const float* Wq = (const float*)d_in[1];
  const float* Wkv = (const float*)d_in[2];
  const float* Wout = (const float*)d_in[3];
  float* out = (float*)d_out;
  char* ws = (char*)d_ws;

  const size_t SEG = 33554432;  // 32 MiB
  unsigned short* Qg = (unsigned short*)ws;
  unsigned short* Kg = (unsigned short*)(ws + SEG);
  unsigned short* Vg = (unsigned short*)(ws + 2 * SEG);
  unsigned short* AO = (unsigned short*)(ws + 3 * SEG);
  unsigned short* xb = AO;  // overlays AO (dead until k_attn writes it)
  float* Pp = (float*)(ws + 2 * SEG);  // partials overlay Vg (dead in outconv)
  unsigned short* WB1 = (unsigned short*)(ws + 4 * SEG);  // ends at 136,183,808

  // WB2: dedicated region if ws allows (convert Wout once); else overlay Qg/Kg
  // and reconvert per batch.
  const size_t WB2_OFF = 136183808;               // WB1 end, 16B-aligned
  const size_t WB2_BYTES = (size_t)1024 * 20480 * 2;
  const bool wb2_once = ws_size >= WB2_OFF + WB2_BYTES;
  unsigned short* WB2 =
      wb2_once ? (unsigned short*)(ws + WB2_OFF) : (unsigned short*)ws;

  k_convw_qkv<<<3840, 256, 0, stream>>>(Wq, Wkv, WB1);
  if (wb2_once) k_convw_out<<<1024, 256, 0, stream>>>(Wout, WB2);
  for (int b = 0; b < 2; b++) {
    k_convx<<<2048, 256, 0, stream>>>(x, xb, b);
    k_qkv<<<dim3(32, 12, 8), 256, 0, stream>>>(xb, WB1, Qg, Kg, Vg);
    k_attn<<<256, 512, 0, stream>>>(Qg, Kg, Vg, AO);
    if (!wb2_once) k_convw_out<<<1024, 256, 0, stream>>>(Wout, WB2);
    k_outconv<<<512, 256, 0, stream>>>(AO, WB2, Pp);
    k_reduce<<<4096, 256, 0, stream>>>(Pp, out, b);
  }
}